// Round 7
// baseline (9724.580 us; speedup 1.0000x reference)
//
#include <hip/hip_runtime.h>
#include <math.h>

// R7: faithful-fp32 encoder+VQ, emulating a numpy float32 transliteration:
//  - convs: sequential fp32 FMA accumulation in im2col order (ci,kh,kw),
//    bias as separate fp32 add, fp32 relu, fp32 storage.
//  - VQ: distances fully in fp32: s1 = sum(round(z*z)) (no FMA), c2 likewise,
//    dot = chained fmaf over d, dist = (s1 + c2[k]) - 2*dot; strict-< argmin.
// Decoder fp32 (outputs 0/1 thresholds are generous).

// -------- K1: conv 4x4 s2 p1, 3->32. x (ce,3,256,256) -> h1 fp32 (ce,32,128,128)
__global__ __launch_bounds__(256) void k_conv1(const float* __restrict__ x, const float* __restrict__ w,
                                               const float* __restrict__ bias, float* __restrict__ out) {
    int t = blockIdx.x * 256 + threadIdx.x;
    int ow = t & 127, oh = (t >> 7) & 127, co = (t >> 14) & 31, b = t >> 19;  // b local to chunk
    float acc = 0.f;
    for (int ci = 0; ci < 3; ci++)
        for (int kh = 0; kh < 4; kh++) {
            int ih = oh * 2 + kh - 1;
            if (ih < 0 || ih > 255) continue;
            for (int kw = 0; kw < 4; kw++) {
                int iw = ow * 2 + kw - 1;
                if (iw < 0 || iw > 255) continue;
                acc = __builtin_fmaf(x[((b * 3 + ci) * 256 + ih) * 256 + iw],
                                     w[((co * 3 + ci) * 4 + kh) * 4 + kw], acc);
            }
        }
    float v = acc + bias[co];      // separate fp32 bias add (y = conv + b)
    out[t] = v > 0.f ? v : 0.f;    // fp32 relu
}

// -------- K2: conv 4x4 s2 p1, 32->64. h1 fp32 -> h2 fp32 (ce,64,64,64)
__global__ __launch_bounds__(256) void k_conv2n(const float* __restrict__ h1, const float* __restrict__ w,
                                                const float* __restrict__ bias, float* __restrict__ out) {
    int t = blockIdx.x * 256 + threadIdx.x;       // ce*64*64*64 threads
    int ow = t & 63, oh = (t >> 6) & 63, co = (t >> 12) & 63, b = t >> 18;
    float acc = 0.f;
    for (int ci = 0; ci < 32; ci++) {
        const float* ip = h1 + ((size_t)(b * 32 + ci)) * 16384;
        const float* wp = w + (co * 32 + ci) * 16;
        for (int kh = 0; kh < 4; kh++) {
            int ih = oh * 2 + kh - 1;
            if (ih < 0 || ih > 127) continue;
            for (int kw = 0; kw < 4; kw++) {
                int iw = ow * 2 + kw - 1;
                if (iw < 0 || iw > 127) continue;
                acc = __builtin_fmaf(ip[ih * 128 + iw], wp[kh * 4 + kw], acc);
            }
        }
    }
    float v = acc + bias[co];
    out[((b * 64 + co) * 64 + oh) * 64 + ow] = v > 0.f ? v : 0.f;
}

// -------- K3: conv 1x1, 64->8. h2 fp32 (ce,64,64,64) -> z fp32 (ce,8,64,64), no relu
__global__ __launch_bounds__(256) void k_conv3(const float* __restrict__ h2, const float* __restrict__ w,
                                               const float* __restrict__ bias, float* __restrict__ zf) {
    __shared__ float wl[8][64];
    __shared__ float bl[8];
    int tid = threadIdx.x;
    for (int i = tid; i < 512; i += 256) wl[i >> 6][i & 63] = w[i];
    if (tid < 8) bl[tid] = bias[tid];
    __syncthreads();
    int t = blockIdx.x * 256 + tid;
    int b = t >> 12, hw = t & 4095;
    float acc[8];
    for (int d = 0; d < 8; d++) acc[d] = 0.f;
    for (int ci = 0; ci < 64; ci++) {                // sequential K=64, FMA (BLAS-like)
        float v = h2[(b * 64 + ci) * 4096 + hw];
        for (int d = 0; d < 8; d++) acc[d] = __builtin_fmaf(v, wl[d][ci], acc[d]);
    }
    for (int d = 0; d < 8; d++)
        zf[(b * 8 + d) * 4096 + hw] = acc[d] + bl[d];
}

// -------- K4: VQ argmin, faithful fp32 distances, first-min tie-break. Full batch.
__global__ __launch_bounds__(256) void k_vq(const float* __restrict__ zf, const float* __restrict__ cb,
                                            int* __restrict__ idx, float* __restrict__ out_idx) {
    __shared__ float cbs[512][8];
    __shared__ float c2s[512];
    int tid = threadIdx.x;
    for (int i = tid; i < 4096; i += 256) cbs[i >> 3][i & 7] = cb[i];
    __syncthreads();
    for (int k = tid; k < 512; k += 256) {
        float s = 0.f;                               // sum(codebook**2): square (rounded), then add
        for (int d = 0; d < 8; d++) {
            float c = cbs[k][d];
            s = s + __fmul_rn(c, c);                 // __fmul_rn blocks FMA contraction
        }
        c2s[k] = s;
    }
    __syncthreads();
    int n = blockIdx.x * 256 + tid;        // pixel in NHWC flat order (b,h,w)
    int b = n >> 12, hw = n & 4095;
    float zv[8], s1 = 0.f;
    for (int d = 0; d < 8; d++) {
        float z = zf[(b * 8 + d) * 4096 + hw];
        zv[d] = z;
        s1 = s1 + __fmul_rn(z, z);                   // sum(z_flat**2): rounded square, then add
    }
    float best = 3.4e38f; int bi = 0;
    for (int k = 0; k < 512; k++) {
        float dot = 0.f;
        for (int d = 0; d < 8; d++) dot = __builtin_fmaf(zv[d], cbs[k][d], dot);  // K=8 fp32 FMA
        float a = s1 + c2s[k];                       // (s1 + c2)
        float dist = a - __fmul_rn(2.0f, dot);       // - 2*dot (2*dot exact; one rounding)
        if (dist < best) { best = dist; bi = k; }
    }
    idx[n] = bi;
    out_idx[n] = (float)bi;
}

// -------- K5: z_q (faithful reshape bug: NHWC-flat gather dropped into NCHW flat) + loss partials.
__global__ __launch_bounds__(256) void k_zq(const int* __restrict__ idx, const float* __restrict__ cb,
                                            const float* __restrict__ zf, float* __restrict__ zq,
                                            double* __restrict__ partial) {
    __shared__ double red[256];
    int t = blockIdx.x * 256 + threadIdx.x;   // 1,048,576
    float q = cb[idx[t >> 3] * 8 + (t & 7)];
    zq[t] = q;
    double d = (double)zf[t] - (double)q;
    red[threadIdx.x] = d * d;
    __syncthreads();
    for (int s = 128; s > 0; s >>= 1) {
        if (threadIdx.x < s) red[threadIdx.x] += red[threadIdx.x + s];
        __syncthreads();
    }
    if (threadIdx.x == 0) partial[blockIdx.x] = red[0];
}

__global__ __launch_bounds__(256) void k_loss_fin(const double* __restrict__ partial, float* __restrict__ out_loss) {
    __shared__ double red[256];
    double s = 0.0;
    for (int i = threadIdx.x; i < 4096; i += 256) s += partial[i];
    red[threadIdx.x] = s;
    __syncthreads();
    for (int st = 128; st > 0; st >>= 1) {
        if (threadIdx.x < st) red[threadIdx.x] += red[threadIdx.x + st];
        __syncthreads();
    }
    if (threadIdx.x == 0)
        out_loss[0] = (float)(1.25 * red[0] / 1048576.0);  // codebook + 0.25*commitment
}

// -------- K7: conv 3x3 p1, 8->64, +bias, relu. zq fp32 (cd,8,64,64) -> d3 fp32 (cd,64,64,64)
__global__ __launch_bounds__(256) void k_dec1(const float* __restrict__ zq, const float* __restrict__ w,
                                              const float* __restrict__ bias, float* __restrict__ out) {
    int t = blockIdx.x * 256 + threadIdx.x;
    int ow = t & 63, oh = (t >> 6) & 63, co = (t >> 12) & 63, b = t >> 18;
    float acc = bias[co];
    for (int ci = 0; ci < 8; ci++)
        for (int kh = 0; kh < 3; kh++) {
            int ih = oh + kh - 1;
            if (ih < 0 || ih > 63) continue;
            for (int kw = 0; kw < 3; kw++) {
                int iw = ow + kw - 1;
                if (iw < 0 || iw > 63) continue;
                acc += zq[((b * 8 + ci) * 64 + ih) * 64 + iw] * w[((co * 8 + ci) * 3 + kh) * 3 + kw];
            }
        }
    out[t] = acc > 0.f ? acc : 0.f;
}

// -------- K8/K9: transposed conv k4 s2 p1 (lhs_dilation=2, pad 2, OIHW, correlation), +bias, relu.
template <int CI, int CO, int HIN>
__global__ __launch_bounds__(256) void k_dect(const float* __restrict__ in, const float* __restrict__ w,
                                              const float* __restrict__ bias, float* __restrict__ out) {
    constexpr int HOUT = HIN * 2;
    int t = blockIdx.x * 256 + threadIdx.x;
    int x = t % HOUT, y = (t / HOUT) % HOUT;
    int co = (t / (HOUT * HOUT)) % CO, b = t / (HOUT * HOUT * CO);
    int px = x & 1, py = y & 1;
    int ih0 = (y >> 1) - 1 + py, ih1 = (y >> 1) + py;
    int kh0 = py, kh1 = py + 2;
    int iw0 = (x >> 1) - 1 + px, iw1 = (x >> 1) + px;
    int kw0 = px, kw1 = px + 2;
    bool vy0 = (ih0 >= 0) & (ih0 < HIN), vy1 = (ih1 >= 0) & (ih1 < HIN);
    bool vx0 = (iw0 >= 0) & (iw0 < HIN), vx1 = (iw1 >= 0) & (iw1 < HIN);
    float acc = bias[co];
    for (int ci = 0; ci < CI; ci++) {
        const float* ip = in + (size_t)(b * CI + ci) * HIN * HIN;
        const float* wp = w + (co * CI + ci) * 16;
        float a00 = (vy0 && vx0) ? ip[ih0 * HIN + iw0] : 0.f;
        float a01 = (vy0 && vx1) ? ip[ih0 * HIN + iw1] : 0.f;
        float a10 = (vy1 && vx0) ? ip[ih1 * HIN + iw0] : 0.f;
        float a11 = (vy1 && vx1) ? ip[ih1 * HIN + iw1] : 0.f;
        acc += a00 * wp[kh0 * 4 + kw0] + a01 * wp[kh0 * 4 + kw1]
             + a10 * wp[kh1 * 4 + kw0] + a11 * wp[kh1 * 4 + kw1];
    }
    out[t] = acc > 0.f ? acc : 0.f;
}

// -------- K10: conv 3x3 p1, 32->3, +bias, sigmoid -> x_recon fp32 (cd,3,256,256)
__global__ __launch_bounds__(256) void k_dec2(const float* __restrict__ in, const float* __restrict__ w,
                                              const float* __restrict__ bias, float* __restrict__ out) {
    int t = blockIdx.x * 256 + threadIdx.x;
    int x = t & 255, y = (t >> 8) & 255;
    int r = t >> 16;                           // b*3 + co
    int co = r % 3, b = r / 3;
    float acc = bias[co];
    for (int ci = 0; ci < 32; ci++)
        for (int kh = 0; kh < 3; kh++) {
            int ih = y + kh - 1;
            if (ih < 0 || ih > 255) continue;
            for (int kw = 0; kw < 3; kw++) {
                int iw = x + kw - 1;
                if (iw < 0 || iw > 255) continue;
                acc += in[((b * 32 + ci) * 256 + ih) * 256 + iw] *
                       w[((co * 32 + ci) * 3 + kh) * 3 + kw];
            }
        }
    out[t] = 1.0f / (1.0f + expf(-acc));
}

extern "C" void kernel_launch(void* const* d_in, const int* in_sizes, int n_in,
                              void* d_out, int out_size, void* d_ws, size_t ws_size,
                              hipStream_t stream) {
    const float* x    = (const float*)d_in[0];
    const float* ew1  = (const float*)d_in[1];
    const float* eb1  = (const float*)d_in[2];
    const float* ew2  = (const float*)d_in[3];
    const float* eb2  = (const float*)d_in[4];
    const float* ew3  = (const float*)d_in[5];
    const float* eb3  = (const float*)d_in[6];
    const float* cb   = (const float*)d_in[7];
    const float* dw1  = (const float*)d_in[8];
    const float* db1  = (const float*)d_in[9];
    const float* dtw1 = (const float*)d_in[10];
    const float* dtb1 = (const float*)d_in[11];
    const float* dtw2 = (const float*)d_in[12];
    const float* dtb2 = (const float*)d_in[13];
    const float* dw2  = (const float*)d_in[14];
    const float* db2  = (const float*)d_in[15];

    // ---- fixed workspace buffers (~8.9 MB) ----
    char* ws = (char*)d_ws;
    float*  z32  = (float*) (ws);               //  4,194,304 B (32,8,64,64) fp32
    float*  zq   = (float*) (ws + 4194304);     //  4,194,304 B
    int*    idx  = (int*)   (ws + 8388608);     //    524,288 B
    double* part = (double*)(ws + 8912896);     //     32,768 B (4096 partials)
    char* region = ws + 8945664;                // shared chunk region

    // ---- adaptive batch chunking (ws_size constant per session -> graph-safe) ----
    size_t fixed = 8945664;
    size_t avail = (ws_size > fixed) ? ws_size - fixed : 0;
    int ce = 32, cd = 32;                                         // samples per chunk (pow2 divisors of 32)
    while (ce > 1 && (size_t)ce * 3145728ull > avail) ce >>= 1;   // enc: h1 fp32 (2 MB) + h2 fp32 (1 MB)
    while (cd > 1 && (size_t)cd * 13631488ull > avail) cd >>= 1;  // dec: d3 (1) + d4 (4) + d5 (8 MB) fp32

    float* h1c = (float*)region;                                  // (ce,32,128,128) fp32
    float* h2c = (float*)(region + (size_t)ce * 2097152ull);      // (ce,64,64,64) fp32
    float* d3c = (float*) region;                                 // (cd,64,64,64) fp32
    float* d4c = (float*) (region + (size_t)cd * 1048576ull);     // (cd,64,128,128) fp32
    float* d5c = (float*) (region + (size_t)cd * 5242880ull);     // (cd,32,256,256) fp32

    float* out      = (float*)d_out;
    float* out_loss = out + 6291456;
    float* out_idx  = out + 6291457;

    // ---- encoder, chunked over batch ----
    for (int c = 0; c < 32 / ce; c++) {
        const float* xc = x + (size_t)c * ce * 196608ull;
        k_conv1<<<ce * 2048, 256, 0, stream>>>(xc, ew1, eb1, h1c);
        k_conv2n<<<ce * 1024, 256, 0, stream>>>(h1c, ew2, eb2, h2c);
        k_conv3<<<ce * 16,   256, 0, stream>>>(h2c, ew3, eb3, z32 + (size_t)c * ce * 32768ull);
    }

    // ---- VQ + loss (full batch) ----
    k_vq<<<512, 256, 0, stream>>>(z32, cb, idx, out_idx);
    k_zq<<<4096, 256, 0, stream>>>(idx, cb, z32, zq, part);
    k_loss_fin<<<1, 256, 0, stream>>>(part, out_loss);

    // ---- decoder, chunked over batch ----
    for (int c = 0; c < 32 / cd; c++) {
        const float* zqc = zq + (size_t)c * cd * 32768ull;
        float* outc = out + (size_t)c * cd * 196608ull;
        k_dec1<<<cd * 1024, 256, 0, stream>>>(zqc, dw1, db1, d3c);
        k_dect<64, 64, 64 ><<<cd * 4096, 256, 0, stream>>>(d3c, dtw1, dtb1, d4c);
        k_dect<64, 32, 128><<<cd * 8192, 256, 0, stream>>>(d4c, dtw2, dtb2, d5c);
        k_dec2<<<cd * 768,  256, 0, stream>>>(d5c, dw2, db2, outc);
    }
}

// Round 8
// 3033.320 us; speedup vs baseline: 3.2059x; 3.2059x over previous
//
#include <hip/hip_runtime.h>
#include <math.h>

// R8: same numerics contract as R7 (faithful-fp32 encoder+VQ, bit-exact FMA
// chain order ci->kh->kw per output; zero-taps as fma(0,w,acc) no-ops).
// All conv kernels restructured for reuse: LDS patch staging (conv2),
// register output-tiling, wave-uniform scalar weight loads.

__device__ __forceinline__ int rfl(int v) { return __builtin_amdgcn_readfirstlane(v); }

// -------- K1: conv 4x4 s2 p1, 3->32. Tile: 4 oh x 2 co per thread.
__global__ __launch_bounds__(256) void k_conv1(const float* __restrict__ x, const float* __restrict__ w,
                                               const float* __restrict__ bias, float* __restrict__ out) {
    int t = blockIdx.x * 256 + threadIdx.x;
    int ow  = t & 127;
    int oh0 = ((t >> 7) & 31) * 4;
    int co0 = rfl((t >> 12) & 15);
    int b   = rfl(t >> 16);
    float acc[4][2] = {};
    for (int ci = 0; ci < 3; ci++) {
        const float* xp  = x + (b * 3 + ci) * 65536;
        const float* wpA = w + (co0 * 3 + ci) * 16;
        const float* wpB = w + ((co0 + 16) * 3 + ci) * 16;
        #pragma unroll
        for (int r = 0; r < 10; r++) {
            int ih = oh0 * 2 - 1 + r;
            bool rok = (ih >= 0) && (ih < 256);
            int ihc = rok ? ih : 0;
            float v[4];
            #pragma unroll
            for (int c = 0; c < 4; c++) {
                int iw = ow * 2 - 1 + c;
                bool ok = rok && (iw >= 0) && (iw < 256);
                int iwc = iw < 0 ? 0 : (iw > 255 ? 255 : iw);
                float vv = xp[ihc * 256 + iwc];
                v[c] = ok ? vv : 0.f;
            }
            #pragma unroll
            for (int o = 0; o < 4; o++) {
                int kh = r - 2 * o;
                if (kh >= 0 && kh < 4) {
                    #pragma unroll
                    for (int kw = 0; kw < 4; kw++) {
                        acc[o][0] = __builtin_fmaf(v[kw], wpA[kh * 4 + kw], acc[o][0]);
                        acc[o][1] = __builtin_fmaf(v[kw], wpB[kh * 4 + kw], acc[o][1]);
                    }
                }
            }
        }
    }
    float bA = bias[co0], bB = bias[co0 + 16];
    #pragma unroll
    for (int o = 0; o < 4; o++) {
        float vA = acc[o][0] + bA, vB = acc[o][1] + bB;
        out[((b * 32 + co0) * 128 + oh0 + o) * 128 + ow]      = vA > 0.f ? vA : 0.f;
        out[((b * 32 + co0 + 16) * 128 + oh0 + o) * 128 + ow] = vB > 0.f ? vB : 0.f;
    }
}

// -------- K2: conv 4x4 s2 p1, 32->64. LDS full-ci patch, wave=16co (chunks of 4).
__global__ __launch_bounds__(256) void k_conv2t(const float* __restrict__ h1, const float* __restrict__ w,
                                                const float* __restrict__ bias, float* __restrict__ out) {
    __shared__ float P[32][18][2][10];   // (ci, r, parity, col): elem (ci,r,c) at [c&1][c>>1]. 46 KB
    int bx = blockIdx.x;
    int b  = bx >> 6;
    int ty = (bx >> 3) & 7, tx = bx & 7;
    int oh0 = ty * 8, ow0 = tx * 8;
    int tid = threadIdx.x;
    for (int i = tid; i < 10368; i += 256) {          // 32*18*18
        int ci = i / 324, rem = i - ci * 324;
        int r = rem / 18, c = rem - r * 18;
        int ih = oh0 * 2 - 1 + r, iw = ow0 * 2 - 1 + c;
        float v = 0.f;
        if (ih >= 0 && ih < 128 && iw >= 0 && iw < 128)
            v = h1[(b * 32 + ci) * 16384 + ih * 128 + iw];
        P[ci][r][c & 1][c >> 1] = v;
    }
    __syncthreads();
    int lane = tid & 63;
    int dy = lane >> 3, dx = lane & 7;
    int co_base = rfl((tid >> 6) * 16);
    int oh = oh0 + dy, ow = ow0 + dx;
    for (int cc = 0; cc < 4; cc++) {
        int co0 = co_base + cc * 4;
        float a0 = 0.f, a1 = 0.f, a2 = 0.f, a3 = 0.f;
        for (int ci = 0; ci < 32; ci++) {
            const float* wp0 = w + ((co0 + 0) * 32 + ci) * 16;
            const float* wp1 = w + ((co0 + 1) * 32 + ci) * 16;
            const float* wp2 = w + ((co0 + 2) * 32 + ci) * 16;
            const float* wp3 = w + ((co0 + 3) * 32 + ci) * 16;
            #pragma unroll
            for (int kh = 0; kh < 4; kh++) {
                int r = 2 * dy + kh;
                float v0 = P[ci][r][0][dx];       // c=2dx   -> kw0
                float v1 = P[ci][r][1][dx];       // c=2dx+1 -> kw1
                float v2 = P[ci][r][0][dx + 1];   // c=2dx+2 -> kw2
                float v3 = P[ci][r][1][dx + 1];   // c=2dx+3 -> kw3
                a0 = __builtin_fmaf(v0, wp0[kh*4+0], a0); a0 = __builtin_fmaf(v1, wp0[kh*4+1], a0);
                a0 = __builtin_fmaf(v2, wp0[kh*4+2], a0); a0 = __builtin_fmaf(v3, wp0[kh*4+3], a0);
                a1 = __builtin_fmaf(v0, wp1[kh*4+0], a1); a1 = __builtin_fmaf(v1, wp1[kh*4+1], a1);
                a1 = __builtin_fmaf(v2, wp1[kh*4+2], a1); a1 = __builtin_fmaf(v3, wp1[kh*4+3], a1);
                a2 = __builtin_fmaf(v0, wp2[kh*4+0], a2); a2 = __builtin_fmaf(v1, wp2[kh*4+1], a2);
                a2 = __builtin_fmaf(v2, wp2[kh*4+2], a2); a2 = __builtin_fmaf(v3, wp2[kh*4+3], a2);
                a3 = __builtin_fmaf(v0, wp3[kh*4+0], a3); a3 = __builtin_fmaf(v1, wp3[kh*4+1], a3);
                a3 = __builtin_fmaf(v2, wp3[kh*4+2], a3); a3 = __builtin_fmaf(v3, wp3[kh*4+3], a3);
            }
        }
        float r0 = a0 + bias[co0 + 0], r1 = a1 + bias[co0 + 1];
        float r2 = a2 + bias[co0 + 2], r3 = a3 + bias[co0 + 3];
        out[((b * 64 + co0 + 0) * 64 + oh) * 64 + ow] = r0 > 0.f ? r0 : 0.f;
        out[((b * 64 + co0 + 1) * 64 + oh) * 64 + ow] = r1 > 0.f ? r1 : 0.f;
        out[((b * 64 + co0 + 2) * 64 + oh) * 64 + ow] = r2 > 0.f ? r2 : 0.f;
        out[((b * 64 + co0 + 3) * 64 + oh) * 64 + ow] = r3 > 0.f ? r3 : 0.f;
    }
}

// -------- K3: conv 1x1, 64->8 (unchanged from R7 — bit-exact path).
__global__ __launch_bounds__(256) void k_conv3(const float* __restrict__ h2, const float* __restrict__ w,
                                               const float* __restrict__ bias, float* __restrict__ zf) {
    __shared__ float wl[8][64];
    __shared__ float bl[8];
    int tid = threadIdx.x;
    for (int i = tid; i < 512; i += 256) wl[i >> 6][i & 63] = w[i];
    if (tid < 8) bl[tid] = bias[tid];
    __syncthreads();
    int t = blockIdx.x * 256 + tid;
    int b = t >> 12, hw = t & 4095;
    float acc[8];
    for (int d = 0; d < 8; d++) acc[d] = 0.f;
    for (int ci = 0; ci < 64; ci++) {
        float v = h2[(b * 64 + ci) * 4096 + hw];
        for (int d = 0; d < 8; d++) acc[d] = __builtin_fmaf(v, wl[d][ci], acc[d]);
    }
    for (int d = 0; d < 8; d++)
        zf[(b * 8 + d) * 4096 + hw] = acc[d] + bl[d];
}

// -------- K4: VQ argmin (unchanged from R7 — bit-exact path).
__global__ __launch_bounds__(256) void k_vq(const float* __restrict__ zf, const float* __restrict__ cb,
                                            int* __restrict__ idx, float* __restrict__ out_idx) {
    __shared__ float cbs[512][8];
    __shared__ float c2s[512];
    int tid = threadIdx.x;
    for (int i = tid; i < 4096; i += 256) cbs[i >> 3][i & 7] = cb[i];
    __syncthreads();
    for (int k = tid; k < 512; k += 256) {
        float s = 0.f;
        for (int d = 0; d < 8; d++) {
            float c = cbs[k][d];
            s = s + __fmul_rn(c, c);
        }
        c2s[k] = s;
    }
    __syncthreads();
    int n = blockIdx.x * 256 + tid;
    int b = n >> 12, hw = n & 4095;
    float zv[8], s1 = 0.f;
    for (int d = 0; d < 8; d++) {
        float z = zf[(b * 8 + d) * 4096 + hw];
        zv[d] = z;
        s1 = s1 + __fmul_rn(z, z);
    }
    float best = 3.4e38f; int bi = 0;
    for (int k = 0; k < 512; k++) {
        float dot = 0.f;
        for (int d = 0; d < 8; d++) dot = __builtin_fmaf(zv[d], cbs[k][d], dot);
        float a = s1 + c2s[k];
        float dist = a - __fmul_rn(2.0f, dot);
        if (dist < best) { best = dist; bi = k; }
    }
    idx[n] = bi;
    out_idx[n] = (float)bi;
}

// -------- K5: z_q (reshape-bug-faithful) + loss partials (unchanged).
__global__ __launch_bounds__(256) void k_zq(const int* __restrict__ idx, const float* __restrict__ cb,
                                            const float* __restrict__ zf, float* __restrict__ zq,
                                            double* __restrict__ partial) {
    __shared__ double red[256];
    int t = blockIdx.x * 256 + threadIdx.x;
    float q = cb[idx[t >> 3] * 8 + (t & 7)];
    zq[t] = q;
    double d = (double)zf[t] - (double)q;
    red[threadIdx.x] = d * d;
    __syncthreads();
    for (int s = 128; s > 0; s >>= 1) {
        if (threadIdx.x < s) red[threadIdx.x] += red[threadIdx.x + s];
        __syncthreads();
    }
    if (threadIdx.x == 0) partial[blockIdx.x] = red[0];
}

__global__ __launch_bounds__(256) void k_loss_fin(const double* __restrict__ partial, float* __restrict__ out_loss) {
    __shared__ double red[256];
    double s = 0.0;
    for (int i = threadIdx.x; i < 4096; i += 256) s += partial[i];
    red[threadIdx.x] = s;
    __syncthreads();
    for (int st = 128; st > 0; st >>= 1) {
        if (threadIdx.x < st) red[threadIdx.x] += red[threadIdx.x + st];
        __syncthreads();
    }
    if (threadIdx.x == 0)
        out_loss[0] = (float)(1.25 * red[0] / 1048576.0);
}

// -------- K7: conv 3x3 p1, 8->64. Tile: 4 oh x 2 co per thread.
__global__ __launch_bounds__(256) void k_dec1(const float* __restrict__ zq, const float* __restrict__ w,
                                              const float* __restrict__ bias, float* __restrict__ out) {
    int t = blockIdx.x * 256 + threadIdx.x;
    int ow  = t & 63;
    int oh0 = ((t >> 6) & 15) * 4;
    int co0 = rfl((t >> 10) & 31);
    int b   = rfl(t >> 15);
    float acc[4][2] = {};
    for (int ci = 0; ci < 8; ci++) {
        const float* ip  = zq + (b * 8 + ci) * 4096;
        const float* wpA = w + (co0 * 8 + ci) * 9;
        const float* wpB = w + ((co0 + 32) * 8 + ci) * 9;
        #pragma unroll
        for (int r = 0; r < 6; r++) {
            int ih = oh0 - 1 + r;
            bool rok = (ih >= 0) && (ih < 64);
            int ihc = rok ? ih : 0;
            float v[3];
            #pragma unroll
            for (int c = 0; c < 3; c++) {
                int iw = ow - 1 + c;
                bool ok = rok && (iw >= 0) && (iw < 64);
                int iwc = iw < 0 ? 0 : (iw > 63 ? 63 : iw);
                float vv = ip[ihc * 64 + iwc];
                v[c] = ok ? vv : 0.f;
            }
            #pragma unroll
            for (int o = 0; o < 4; o++) {
                int kh = r - o;
                if (kh >= 0 && kh < 3) {
                    #pragma unroll
                    for (int kw = 0; kw < 3; kw++) {
                        acc[o][0] = __builtin_fmaf(v[kw], wpA[kh * 3 + kw], acc[o][0]);
                        acc[o][1] = __builtin_fmaf(v[kw], wpB[kh * 3 + kw], acc[o][1]);
                    }
                }
            }
        }
    }
    float bA = bias[co0], bB = bias[co0 + 32];
    #pragma unroll
    for (int o = 0; o < 4; o++) {
        float vA = acc[o][0] + bA, vB = acc[o][1] + bB;
        out[((b * 64 + co0) * 64 + oh0 + o) * 64 + ow]      = vA > 0.f ? vA : 0.f;
        out[((b * 64 + co0 + 32) * 64 + oh0 + o) * 64 + ow] = vB > 0.f ? vB : 0.f;
    }
}

// -------- K8/K9: transposed conv k4 s2 p1. 4x4 output tile (2x2 input pos x 4 quadrants).
template <int CI, int CO, int HIN, int LNT, int LCO>
__global__ __launch_bounds__(256) void k_dect(const float* __restrict__ in, const float* __restrict__ w,
                                              const float* __restrict__ bias, float* __restrict__ out) {
    constexpr int HOUT = HIN * 2;
    int t = blockIdx.x * 256 + threadIdx.x;
    int tx = t & ((1 << LNT) - 1);
    int ty = (t >> LNT) & ((1 << LNT) - 1);
    int co = rfl((t >> (2 * LNT)) & (CO - 1));
    int b  = rfl(t >> (2 * LNT + LCO));
    int rofs[4]; bool rok[4]; int cofs[4]; bool cok[4];
    #pragma unroll
    for (int p = 0; p < 4; p++) {
        int ih = 2 * ty - 1 + p;
        rok[p] = (ih >= 0) && (ih < HIN);
        rofs[p] = (rok[p] ? ih : 0) * HIN;
        int iw = 2 * tx - 1 + p;
        cok[p] = (iw >= 0) && (iw < HIN);
        cofs[p] = cok[p] ? iw : 0;
    }
    float acc[4][4] = {};
    for (int ci = 0; ci < CI; ci++) {
        const float* ip = in + (size_t)(b * CI + ci) * (HIN * HIN);
        const float* wp = w + (co * CI + ci) * 16;
        float Pv[4][4];
        #pragma unroll
        for (int p = 0; p < 4; p++)
            #pragma unroll
            for (int q = 0; q < 4; q++) {
                float vv = ip[rofs[p] + cofs[q]];
                Pv[p][q] = (rok[p] && cok[q]) ? vv : 0.f;
            }
        #pragma unroll
        for (int dy = 0; dy < 4; dy++) {
            int py = dy & 1, p0 = (dy >> 1) + py;
            #pragma unroll
            for (int dx = 0; dx < 4; dx++) {
                int px = dx & 1, q0 = (dx >> 1) + px;
                float a = acc[dy][dx];
                a = __builtin_fmaf(Pv[p0][q0],     wp[py * 4 + px],           a);
                a = __builtin_fmaf(Pv[p0][q0 + 1], wp[py * 4 + px + 2],       a);
                a = __builtin_fmaf(Pv[p0 + 1][q0],     wp[(py + 2) * 4 + px],     a);
                a = __builtin_fmaf(Pv[p0 + 1][q0 + 1], wp[(py + 2) * 4 + px + 2], a);
                acc[dy][dx] = a;
            }
        }
    }
    float bv = bias[co];
    #pragma unroll
    for (int dy = 0; dy < 4; dy++) {
        int y = 4 * ty + dy;
        #pragma unroll
        for (int dx = 0; dx < 4; dx++) {
            int xx = 4 * tx + dx;
            float v = acc[dy][dx] + bv;
            out[((size_t)(b * CO + co) * HOUT + y) * HOUT + xx] = v > 0.f ? v : 0.f;
        }
    }
}

// -------- K10: conv 3x3 p1, 32->3, sigmoid. Tile: 4 y per thread.
__global__ __launch_bounds__(256) void k_dec2(const float* __restrict__ in, const float* __restrict__ w,
                                              const float* __restrict__ bias, float* __restrict__ out) {
    int t = blockIdx.x * 256 + threadIdx.x;
    int x  = t & 255;
    int y0 = ((t >> 8) & 63) * 4;
    int r  = rfl(t >> 14);
    int co = r % 3, b = r / 3;
    float acc[4] = {};
    for (int ci = 0; ci < 32; ci++) {
        const float* ip = in + (size_t)(b * 32 + ci) * 65536;
        const float* wp = w + (co * 32 + ci) * 9;
        #pragma unroll
        for (int rr = 0; rr < 6; rr++) {
            int ih = y0 - 1 + rr;
            bool rok = (ih >= 0) && (ih < 256);
            int ihc = rok ? ih : 0;
            float v[3];
            #pragma unroll
            for (int c = 0; c < 3; c++) {
                int iw = x - 1 + c;
                bool ok = rok && (iw >= 0) && (iw < 256);
                int iwc = iw < 0 ? 0 : (iw > 255 ? 255 : iw);
                float vv = ip[ihc * 256 + iwc];
                v[c] = ok ? vv : 0.f;
            }
            #pragma unroll
            for (int o = 0; o < 4; o++) {
                int kh = rr - o;
                if (kh >= 0 && kh < 3) {
                    #pragma unroll
                    for (int kw = 0; kw < 3; kw++)
                        acc[o] = __builtin_fmaf(v[kw], wp[kh * 3 + kw], acc[o]);
                }
            }
        }
    }
    float bv = bias[co];
    #pragma unroll
    for (int o = 0; o < 4; o++) {
        float v = acc[o] + bv;
        out[((size_t)(b * 3 + co) * 256 + y0 + o) * 256 + x] = 1.0f / (1.0f + expf(-v));
    }
}

extern "C" void kernel_launch(void* const* d_in, const int* in_sizes, int n_in,
                              void* d_out, int out_size, void* d_ws, size_t ws_size,
                              hipStream_t stream) {
    const float* x    = (const float*)d_in[0];
    const float* ew1  = (const float*)d_in[1];
    const float* eb1  = (const float*)d_in[2];
    const float* ew2  = (const float*)d_in[3];
    const float* eb2  = (const float*)d_in[4];
    const float* ew3  = (const float*)d_in[5];
    const float* eb3  = (const float*)d_in[6];
    const float* cb   = (const float*)d_in[7];
    const float* dw1  = (const float*)d_in[8];
    const float* db1  = (const float*)d_in[9];
    const float* dtw1 = (const float*)d_in[10];
    const float* dtb1 = (const float*)d_in[11];
    const float* dtw2 = (const float*)d_in[12];
    const float* dtb2 = (const float*)d_in[13];
    const float* dw2  = (const float*)d_in[14];
    const float* db2  = (const float*)d_in[15];

    char* ws = (char*)d_ws;
    float*  z32  = (float*) (ws);               //  4,194,304 B (32,8,64,64)
    float*  zq   = (float*) (ws + 4194304);     //  4,194,304 B
    int*    idx  = (int*)   (ws + 8388608);     //    524,288 B
    double* part = (double*)(ws + 8912896);     //     32,768 B
    char* region = ws + 8945664;

    size_t fixed = 8945664;
    size_t avail = (ws_size > fixed) ? ws_size - fixed : 0;
    int ce = 32, cd = 32;
    while (ce > 1 && (size_t)ce * 3145728ull > avail) ce >>= 1;   // h1(2MB) + h2(1MB)
    while (cd > 1 && (size_t)cd * 13631488ull > avail) cd >>= 1;  // d3(1) + d4(4) + d5(8MB)

    float* h1c = (float*)region;                                  // (ce,32,128,128)
    float* h2c = (float*)(region + (size_t)ce * 2097152ull);      // (ce,64,64,64)
    float* d3c = (float*) region;                                 // (cd,64,64,64)
    float* d4c = (float*) (region + (size_t)cd * 1048576ull);     // (cd,64,128,128)
    float* d5c = (float*) (region + (size_t)cd * 5242880ull);     // (cd,32,256,256)

    float* out      = (float*)d_out;
    float* out_loss = out + 6291456;
    float* out_idx  = out + 6291457;

    for (int c = 0; c < 32 / ce; c++) {
        const float* xc = x + (size_t)c * ce * 196608ull;
        k_conv1<<<ce * 256, 256, 0, stream>>>(xc, ew1, eb1, h1c);
        k_conv2t<<<ce * 64, 256, 0, stream>>>(h1c, ew2, eb2, h2c);
        k_conv3<<<ce * 16,  256, 0, stream>>>(h2c, ew3, eb3, z32 + (size_t)c * ce * 32768ull);
    }

    k_vq<<<512, 256, 0, stream>>>(z32, cb, idx, out_idx);
    k_zq<<<4096, 256, 0, stream>>>(idx, cb, z32, zq, part);
    k_loss_fin<<<1, 256, 0, stream>>>(part, out_loss);

    for (int c = 0; c < 32 / cd; c++) {
        const float* zqc = zq + (size_t)c * cd * 32768ull;
        float* outc = out + (size_t)c * cd * 196608ull;
        k_dec1<<<cd * 128, 256, 0, stream>>>(zqc, dw1, db1, d3c);
        k_dect<64, 64, 64, 5, 6><<<cd * 256, 256, 0, stream>>>(d3c, dtw1, dtb1, d4c);
        k_dect<64, 32, 128, 6, 5><<<cd * 512, 256, 0, stream>>>(d4c, dtw2, dtb2, d5c);
        k_dec2<<<cd * 192, 256, 0, stream>>>(d5c, dw2, db2, outc);
    }
}

// Round 9
// 1078.989 us; speedup vs baseline: 9.0127x; 2.8113x over previous
//
#include <hip/hip_runtime.h>
#include <hip/hip_bf16.h>
#include <math.h>

// R9: encoder+VQ unchanged (bit-exact fp32, matches np argmin). Decoder
// transposed convs rewritten as bf16 MFMA implicit GEMM per parity quadrant:
//   out(2i+py, 2j+px)[co] = sum_ci sum_{dy,dx} in[ci][i-1+py+dy][j-1+px+dx]
//                                      * w[co][ci][py+2dy][px+2dx]
// K = tap*64+ci (tap=dy*2+dx) so A-fragments are ci-contiguous ds_read_b128.
// Weights pre-packed to B-fragment order by k_wprep (runs every launch).
// absmax channel: ~0.01 => bf16-correct decoder; ~0.5 => layout bug.

__device__ __forceinline__ int rfl(int v) { return __builtin_amdgcn_readfirstlane(v); }

typedef __attribute__((ext_vector_type(8))) short s8v;
typedef __attribute__((ext_vector_type(4))) float f4v;

__device__ __forceinline__ ushort f2bf(float f) {
    __hip_bfloat16 h = __float2bfloat16(f);
    return *(ushort*)&h;
}

// -------- K1: conv 4x4 s2 p1, 3->32. Tile: 4 oh x 2 co per thread. (bit-exact)
__global__ __launch_bounds__(256) void k_conv1(const float* __restrict__ x, const float* __restrict__ w,
                                               const float* __restrict__ bias, float* __restrict__ out) {
    int t = blockIdx.x * 256 + threadIdx.x;
    int ow  = t & 127;
    int oh0 = ((t >> 7) & 31) * 4;
    int co0 = rfl((t >> 12) & 15);
    int b   = rfl(t >> 16);
    float acc[4][2] = {};
    for (int ci = 0; ci < 3; ci++) {
        const float* xp  = x + (b * 3 + ci) * 65536;
        const float* wpA = w + (co0 * 3 + ci) * 16;
        const float* wpB = w + ((co0 + 16) * 3 + ci) * 16;
        #pragma unroll
        for (int r = 0; r < 10; r++) {
            int ih = oh0 * 2 - 1 + r;
            bool rok = (ih >= 0) && (ih < 256);
            int ihc = rok ? ih : 0;
            float v[4];
            #pragma unroll
            for (int c = 0; c < 4; c++) {
                int iw = ow * 2 - 1 + c;
                bool ok = rok && (iw >= 0) && (iw < 256);
                int iwc = iw < 0 ? 0 : (iw > 255 ? 255 : iw);
                float vv = xp[ihc * 256 + iwc];
                v[c] = ok ? vv : 0.f;
            }
            #pragma unroll
            for (int o = 0; o < 4; o++) {
                int kh = r - 2 * o;
                if (kh >= 0 && kh < 4) {
                    #pragma unroll
                    for (int kw = 0; kw < 4; kw++) {
                        acc[o][0] = __builtin_fmaf(v[kw], wpA[kh * 4 + kw], acc[o][0]);
                        acc[o][1] = __builtin_fmaf(v[kw], wpB[kh * 4 + kw], acc[o][1]);
                    }
                }
            }
        }
    }
    float bA = bias[co0], bB = bias[co0 + 16];
    #pragma unroll
    for (int o = 0; o < 4; o++) {
        float vA = acc[o][0] + bA, vB = acc[o][1] + bB;
        out[((b * 32 + co0) * 128 + oh0 + o) * 128 + ow]      = vA > 0.f ? vA : 0.f;
        out[((b * 32 + co0 + 16) * 128 + oh0 + o) * 128 + ow] = vB > 0.f ? vB : 0.f;
    }
}

// -------- K2: conv 4x4 s2 p1, 32->64. LDS patch, bit-exact FMA order.
__global__ __launch_bounds__(256) void k_conv2t(const float* __restrict__ h1, const float* __restrict__ w,
                                                const float* __restrict__ bias, float* __restrict__ out) {
    __shared__ float P[32][18][2][10];
    int bx = blockIdx.x;
    int b  = bx >> 6;
    int ty = (bx >> 3) & 7, tx = bx & 7;
    int oh0 = ty * 8, ow0 = tx * 8;
    int tid = threadIdx.x;
    for (int i = tid; i < 10368; i += 256) {
        int ci = i / 324, rem = i - ci * 324;
        int r = rem / 18, c = rem - r * 18;
        int ih = oh0 * 2 - 1 + r, iw = ow0 * 2 - 1 + c;
        float v = 0.f;
        if (ih >= 0 && ih < 128 && iw >= 0 && iw < 128)
            v = h1[(b * 32 + ci) * 16384 + ih * 128 + iw];
        P[ci][r][c & 1][c >> 1] = v;
    }
    __syncthreads();
    int lane = tid & 63;
    int dy = lane >> 3, dx = lane & 7;
    int co_base = rfl((tid >> 6) * 16);
    int oh = oh0 + dy, ow = ow0 + dx;
    for (int cc = 0; cc < 4; cc++) {
        int co0 = co_base + cc * 4;
        float a0 = 0.f, a1 = 0.f, a2 = 0.f, a3 = 0.f;
        for (int ci = 0; ci < 32; ci++) {
            const float* wp0 = w + ((co0 + 0) * 32 + ci) * 16;
            const float* wp1 = w + ((co0 + 1) * 32 + ci) * 16;
            const float* wp2 = w + ((co0 + 2) * 32 + ci) * 16;
            const float* wp3 = w + ((co0 + 3) * 32 + ci) * 16;
            #pragma unroll
            for (int kh = 0; kh < 4; kh++) {
                int r = 2 * dy + kh;
                float v0 = P[ci][r][0][dx];
                float v1 = P[ci][r][1][dx];
                float v2 = P[ci][r][0][dx + 1];
                float v3 = P[ci][r][1][dx + 1];
                a0 = __builtin_fmaf(v0, wp0[kh*4+0], a0); a0 = __builtin_fmaf(v1, wp0[kh*4+1], a0);
                a0 = __builtin_fmaf(v2, wp0[kh*4+2], a0); a0 = __builtin_fmaf(v3, wp0[kh*4+3], a0);
                a1 = __builtin_fmaf(v0, wp1[kh*4+0], a1); a1 = __builtin_fmaf(v1, wp1[kh*4+1], a1);
                a1 = __builtin_fmaf(v2, wp1[kh*4+2], a1); a1 = __builtin_fmaf(v3, wp1[kh*4+3], a1);
                a2 = __builtin_fmaf(v0, wp2[kh*4+0], a2); a2 = __builtin_fmaf(v1, wp2[kh*4+1], a2);
                a2 = __builtin_fmaf(v2, wp2[kh*4+2], a2); a2 = __builtin_fmaf(v3, wp2[kh*4+3], a2);
                a3 = __builtin_fmaf(v0, wp3[kh*4+0], a3); a3 = __builtin_fmaf(v1, wp3[kh*4+1], a3);
                a3 = __builtin_fmaf(v2, wp3[kh*4+2], a3); a3 = __builtin_fmaf(v3, wp3[kh*4+3], a3);
            }
        }
        float r0 = a0 + bias[co0 + 0], r1 = a1 + bias[co0 + 1];
        float r2 = a2 + bias[co0 + 2], r3 = a3 + bias[co0 + 3];
        out[((b * 64 + co0 + 0) * 64 + oh) * 64 + ow] = r0 > 0.f ? r0 : 0.f;
        out[((b * 64 + co0 + 1) * 64 + oh) * 64 + ow] = r1 > 0.f ? r1 : 0.f;
        out[((b * 64 + co0 + 2) * 64 + oh) * 64 + ow] = r2 > 0.f ? r2 : 0.f;
        out[((b * 64 + co0 + 3) * 64 + oh) * 64 + ow] = r3 > 0.f ? r3 : 0.f;
    }
}

// -------- K3: conv 1x1, 64->8 (bit-exact).
__global__ __launch_bounds__(256) void k_conv3(const float* __restrict__ h2, const float* __restrict__ w,
                                               const float* __restrict__ bias, float* __restrict__ zf) {
    __shared__ float wl[8][64];
    __shared__ float bl[8];
    int tid = threadIdx.x;
    for (int i = tid; i < 512; i += 256) wl[i >> 6][i & 63] = w[i];
    if (tid < 8) bl[tid] = bias[tid];
    __syncthreads();
    int t = blockIdx.x * 256 + tid;
    int b = t >> 12, hw = t & 4095;
    float acc[8];
    for (int d = 0; d < 8; d++) acc[d] = 0.f;
    for (int ci = 0; ci < 64; ci++) {
        float v = h2[(b * 64 + ci) * 4096 + hw];
        for (int d = 0; d < 8; d++) acc[d] = __builtin_fmaf(v, wl[d][ci], acc[d]);
    }
    for (int d = 0; d < 8; d++)
        zf[(b * 8 + d) * 4096 + hw] = acc[d] + bl[d];
}

// -------- K4: VQ argmin (bit-exact).
__global__ __launch_bounds__(256) void k_vq(const float* __restrict__ zf, const float* __restrict__ cb,
                                            int* __restrict__ idx, float* __restrict__ out_idx) {
    __shared__ float cbs[512][8];
    __shared__ float c2s[512];
    int tid = threadIdx.x;
    for (int i = tid; i < 4096; i += 256) cbs[i >> 3][i & 7] = cb[i];
    __syncthreads();
    for (int k = tid; k < 512; k += 256) {
        float s = 0.f;
        for (int d = 0; d < 8; d++) {
            float c = cbs[k][d];
            s = s + __fmul_rn(c, c);
        }
        c2s[k] = s;
    }
    __syncthreads();
    int n = blockIdx.x * 256 + tid;
    int b = n >> 12, hw = n & 4095;
    float zv[8], s1 = 0.f;
    for (int d = 0; d < 8; d++) {
        float z = zf[(b * 8 + d) * 4096 + hw];
        zv[d] = z;
        s1 = s1 + __fmul_rn(z, z);
    }
    float best = 3.4e38f; int bi = 0;
    for (int k = 0; k < 512; k++) {
        float dot = 0.f;
        for (int d = 0; d < 8; d++) dot = __builtin_fmaf(zv[d], cbs[k][d], dot);
        float a = s1 + c2s[k];
        float dist = a - __fmul_rn(2.0f, dot);
        if (dist < best) { best = dist; bi = k; }
    }
    idx[n] = bi;
    out_idx[n] = (float)bi;
}

// -------- K5: z_q + loss partials (unchanged).
__global__ __launch_bounds__(256) void k_zq(const int* __restrict__ idx, const float* __restrict__ cb,
                                            const float* __restrict__ zf, float* __restrict__ zq,
                                            double* __restrict__ partial) {
    __shared__ double red[256];
    int t = blockIdx.x * 256 + threadIdx.x;
    float q = cb[idx[t >> 3] * 8 + (t & 7)];
    zq[t] = q;
    double d = (double)zf[t] - (double)q;
    red[threadIdx.x] = d * d;
    __syncthreads();
    for (int s = 128; s > 0; s >>= 1) {
        if (threadIdx.x < s) red[threadIdx.x] += red[threadIdx.x + s];
        __syncthreads();
    }
    if (threadIdx.x == 0) partial[blockIdx.x] = red[0];
}

__global__ __launch_bounds__(256) void k_loss_fin(const double* __restrict__ partial, float* __restrict__ out_loss) {
    __shared__ double red[256];
    double s = 0.0;
    for (int i = threadIdx.x; i < 4096; i += 256) s += partial[i];
    red[threadIdx.x] = s;
    __syncthreads();
    for (int st = 128; st > 0; st >>= 1) {
        if (threadIdx.x < st) red[threadIdx.x] += red[threadIdx.x + st];
        __syncthreads();
    }
    if (threadIdx.x == 0)
        out_loss[0] = (float)(1.25 * red[0] / 1048576.0);
}

// -------- K7: conv 3x3 p1, 8->64 (unchanged fp32).
__global__ __launch_bounds__(256) void k_dec1(const float* __restrict__ zq, const float* __restrict__ w,
                                              const float* __restrict__ bias, float* __restrict__ out) {
    int t = blockIdx.x * 256 + threadIdx.x;
    int ow  = t & 63;
    int oh0 = ((t >> 6) & 15) * 4;
    int co0 = rfl((t >> 10) & 31);
    int b   = rfl(t >> 15);
    float acc[4][2] = {};
    for (int ci = 0; ci < 8; ci++) {
        const float* ip  = zq + (b * 8 + ci) * 4096;
        const float* wpA = w + (co0 * 8 + ci) * 9;
        const float* wpB = w + ((co0 + 32) * 8 + ci) * 9;
        #pragma unroll
        for (int r = 0; r < 6; r++) {
            int ih = oh0 - 1 + r;
            bool rok = (ih >= 0) && (ih < 64);
            int ihc = rok ? ih : 0;
            float v[3];
            #pragma unroll
            for (int c = 0; c < 3; c++) {
                int iw = ow - 1 + c;
                bool ok = rok && (iw >= 0) && (iw < 64);
                int iwc = iw < 0 ? 0 : (iw > 63 ? 63 : iw);
                float vv = ip[ihc * 64 + iwc];
                v[c] = ok ? vv : 0.f;
            }
            #pragma unroll
            for (int o = 0; o < 4; o++) {
                int kh = r - o;
                if (kh >= 0 && kh < 3) {
                    #pragma unroll
                    for (int kw = 0; kw < 3; kw++) {
                        acc[o][0] = __builtin_fmaf(v[kw], wpA[kh * 3 + kw], acc[o][0]);
                        acc[o][1] = __builtin_fmaf(v[kw], wpB[kh * 3 + kw], acc[o][1]);
                    }
                }
            }
        }
    }
    float bA = bias[co0], bB = bias[co0 + 32];
    #pragma unroll
    for (int o = 0; o < 4; o++) {
        float vA = acc[o][0] + bA, vB = acc[o][1] + bB;
        out[((b * 64 + co0) * 64 + oh0 + o) * 64 + ow]      = vA > 0.f ? vA : 0.f;
        out[((b * 64 + co0 + 32) * 64 + oh0 + o) * 64 + ow] = vB > 0.f ? vB : 0.f;
    }
}

// -------- Weight prep: repack transposed-conv weights to B-fragment order.
// Wf[q][nt][kt][lane][jj] = bf16( w[co=nt*16+(lane&15)][ci][py+2dy][px+2dx] )
// with k = kt*32 + (lane>>4)*8 + jj, tap = kt>>1 (=dy*2+dx), ci = (kt&1)*32+(lane>>4)*8+jj.
template <int CI, int CO>
__global__ __launch_bounds__(256) void k_wprep(const float* __restrict__ w, ushort* __restrict__ Wf) {
    constexpr int NT = CO / 16;
    int t = blockIdx.x * 256 + threadIdx.x;
    if (t >= 4 * NT * 8 * 64) return;
    int lane = t & 63;
    int kt = (t >> 6) & 7;
    int nt = (t >> 9) % NT;
    int q  = t / (512 * NT);
    int py = q >> 1, px = q & 1;
    int n = nt * 16 + (lane & 15);
    int cb = (kt & 1) * 32 + (lane >> 4) * 8;
    int tap = kt >> 1, dy = tap >> 1, dx = tap & 1;
    #pragma unroll
    for (int jj = 0; jj < 8; jj++) {
        int ci = cb + jj;
        float v = w[((n * CI + ci) * 4 + (py + 2 * dy)) * 4 + (px + 2 * dx)];
        Wf[(((q * NT + nt) * 8 + kt) * 64 + lane) * 8 + jj] = f2bf(v);
    }
}

// -------- K8/K9: transposed conv k4 s2 p1 via bf16 MFMA implicit GEMM.
// Block = one sample x one 16x16 quadrant-tile (32x32 output region). Wave = quadrant.
template <int CI, int CO, int HIN>
__global__ __launch_bounds__(256) void k_dect_mfma(const float* __restrict__ in, const ushort* __restrict__ Wf,
                                                   const float* __restrict__ bias, float* __restrict__ out) {
    constexpr int NT = CO / 16;
    constexpr int TILES = HIN / 16;
    constexpr int HOUT = 2 * HIN;
    __shared__ alignas(16) ushort L[18 * 18 * 72];   // [row][col][ci], stride 72 (16B-aligned slots)
    int blk = blockIdx.x;
    int b = blk / (TILES * TILES);
    int tile = blk - b * (TILES * TILES);
    int i0 = (tile / TILES) * 16, j0 = (tile % TILES) * 16;
    const float* ip = in + (size_t)b * CI * HIN * HIN;
    for (int e = threadIdx.x; e < 18 * 18 * CI; e += 256) {
        int ci = e / 324; int rem = e - ci * 324;
        int row = rem / 18; int col = rem - row * 18;
        int ih = i0 - 1 + row, iw = j0 - 1 + col;
        float v = 0.f;
        if (ih >= 0 && ih < HIN && iw >= 0 && iw < HIN)
            v = ip[(size_t)ci * (HIN * HIN) + ih * HIN + iw];
        L[(row * 18 + col) * 72 + ci] = f2bf(v);
    }
    __syncthreads();
    int wv = threadIdx.x >> 6;          // wave id = quadrant q
    int lane = threadIdx.x & 63;
    int py = wv >> 1, px = wv & 1;
    int m = lane & 15, quad = lane >> 4;
    const ushort* wq = Wf + (size_t)wv * NT * 8 * 64 * 8;
    for (int il = 0; il < 16; il++) {
        s8v a[8];
        #pragma unroll
        for (int kt = 0; kt < 8; kt++) {
            int tap = kt >> 1, dy = tap >> 1, dx = tap & 1;
            int r = il + py + dy, cl = m + px + dx;
            a[kt] = *(s8v*)&L[(r * 18 + cl) * 72 + (kt & 1) * 32 + quad * 8];
        }
        #pragma unroll
        for (int nt = 0; nt < NT; nt++) {
            f4v acc = {0.f, 0.f, 0.f, 0.f};
            #pragma unroll
            for (int kt = 0; kt < 8; kt++) {
                s8v bf = *(const s8v*)&wq[((nt * 8 + kt) * 64 + lane) * 8];
                acc = __builtin_amdgcn_mfma_f32_16x16x32_bf16(a[kt], bf, acc, 0, 0, 0);
            }
            int co = nt * 16 + m;                 // D: col = lane&15 = co
            float bv = bias[co];
            int y = 2 * (i0 + il) + py;
            #pragma unroll
            for (int reg = 0; reg < 4; reg++) {
                int jD = j0 + quad * 4 + reg;     // D: row = quad*4+reg = pixel
                int xx = 2 * jD + px;
                float v = acc[reg] + bv;
                out[((size_t)(b * CO + co) * HOUT + y) * HOUT + xx] = v > 0.f ? v : 0.f;
            }
        }
    }
}

// -------- K10: conv 3x3 p1, 32->3, sigmoid (unchanged fp32).
__global__ __launch_bounds__(256) void k_dec2(const float* __restrict__ in, const float* __restrict__ w,
                                              const float* __restrict__ bias, float* __restrict__ out) {
    int t = blockIdx.x * 256 + threadIdx.x;
    int x  = t & 255;
    int y0 = ((t >> 8) & 63) * 4;
    int r  = rfl(t >> 14);
    int co = r % 3, b = r / 3;
    float acc[4] = {};
    for (int ci = 0; ci < 32; ci++) {
        const float* ip = in + (size_t)(b * 32 + ci) * 65536;
        const float* wp = w + (co * 32 + ci) * 9;
        #pragma unroll
        for (int rr = 0; rr < 6; rr++) {
            int ih = y0 - 1 + rr;
            bool rok = (ih >= 0) && (ih < 256);
            int ihc = rok ? ih : 0;
            float v[3];
            #pragma unroll
            for (int c = 0; c < 3; c++) {
                int iw = x - 1 + c;
                bool ok = rok && (iw >= 0) && (iw < 256);
                int iwc = iw < 0 ? 0 : (iw > 255 ? 255 : iw);
                float vv = ip[ihc * 256 + iwc];
                v[c] = ok ? vv : 0.f;
            }
            #pragma unroll
            for (int o = 0; o < 4; o++) {
                int kh = rr - o;
                if (kh >= 0 && kh < 3) {
                    #pragma unroll
                    for (int kw = 0; kw < 3; kw++)
                        acc[o] = __builtin_fmaf(v[kw], wp[kh * 3 + kw], acc[o]);
                }
            }
        }
    }
    float bv = bias[co];
    #pragma unroll
    for (int o = 0; o < 4; o++) {
        float v = acc[o] + bv;
        out[((size_t)(b * 3 + co) * 256 + y0 + o) * 256 + x] = 1.0f / (1.0f + expf(-v));
    }
}

extern "C" void kernel_launch(void* const* d_in, const int* in_sizes, int n_in,
                              void* d_out, int out_size, void* d_ws, size_t ws_size,
                              hipStream_t stream) {
    const float* x    = (const float*)d_in[0];
    const float* ew1  = (const float*)d_in[1];
    const float* eb1  = (const float*)d_in[2];
    const float* ew2  = (const float*)d_in[3];
    const float* eb2  = (const float*)d_in[4];
    const float* ew3  = (const float*)d_in[5];
    const float* eb3  = (const float*)d_in[6];
    const float* cb   = (const float*)d_in[7];
    const float* dw1  = (const float*)d_in[8];
    const float* db1  = (const float*)d_in[9];
    const float* dtw1 = (const float*)d_in[10];
    const float* dtb1 = (const float*)d_in[11];
    const float* dtw2 = (const float*)d_in[12];
    const float* dtb2 = (const float*)d_in[13];
    const float* dw2  = (const float*)d_in[14];
    const float* db2  = (const float*)d_in[15];

    char* ws = (char*)d_ws;
    float*  z32  = (float*) (ws);               //  4,194,304 B
    float*  zq   = (float*) (ws + 4194304);     //  4,194,304 B
    int*    idx  = (int*)   (ws + 8388608);     //    524,288 B
    double* part = (double*)(ws + 8912896);     //     32,768 B
    ushort* Wf1  = (ushort*)(ws + 8945664);     //    131,072 B (4q x 4nt x 8kt x 64 x 8)
    ushort* Wf2  = (ushort*)(ws + 9076736);     //     65,536 B (4q x 2nt x 8kt x 64 x 8)
    char* region = ws + 9142272;

    size_t fixed = 9142272;
    size_t avail = (ws_size > fixed) ? ws_size - fixed : 0;
    int ce = 32, cd = 32;
    while (ce > 1 && (size_t)ce * 3145728ull > avail) ce >>= 1;   // h1(2MB)+h2(1MB)
    while (cd > 1 && (size_t)cd * 13631488ull > avail) cd >>= 1;  // d3(1)+d4(4)+d5(8MB)

    float* h1c = (float*)region;                                  // (ce,32,128,128)
    float* h2c = (float*)(region + (size_t)ce * 2097152ull);      // (ce,64,64,64)
    float* d3c = (float*) region;                                 // (cd,64,64,64)
    float* d4c = (float*) (region + (size_t)cd * 1048576ull);     // (cd,64,128,128)
    float* d5c = (float*) (region + (size_t)cd * 5242880ull);     // (cd,32,256,256)

    float* out      = (float*)d_out;
    float* out_loss = out + 6291456;
    float* out_idx  = out + 6291457;

    for (int c = 0; c < 32 / ce; c++) {
        const float* xc = x + (size_t)c * ce * 196608ull;
        k_conv1<<<ce * 256, 256, 0, stream>>>(xc, ew1, eb1, h1c);
        k_conv2t<<<ce * 64, 256, 0, stream>>>(h1c, ew2, eb2, h2c);
        k_conv3<<<ce * 16,  256, 0, stream>>>(h2c, ew3, eb3, z32 + (size_t)c * ce * 32768ull);
    }

    k_vq<<<512, 256, 0, stream>>>(z32, cb, idx, out_idx);
    k_zq<<<4096, 256, 0, stream>>>(idx, cb, z32, zq, part);
    k_loss_fin<<<1, 256, 0, stream>>>(part, out_loss);

    // weight repack for MFMA dect kernels (tiny; every launch, graph-safe)
    k_wprep<64, 64><<<32, 256, 0, stream>>>(dtw1, Wf1);
    k_wprep<64, 32><<<16, 256, 0, stream>>>(dtw2, Wf2);

    for (int c = 0; c < 32 / cd; c++) {
        const float* zqc = zq + (size_t)c * cd * 32768ull;
        float* outc = out + (size_t)c * cd * 196608ull;
        k_dec1<<<cd * 128, 256, 0, stream>>>(zqc, dw1, db1, d3c);
        k_dect_mfma<64, 64, 64 ><<<cd * 16, 256, 0, stream>>>(d3c, Wf1, dtb1, d4c);
        k_dect_mfma<64, 32, 128><<<cd * 64, 256, 0, stream>>>(d4c, Wf2, dtb2, d5c);
        k_dec2<<<cd * 192, 256, 0, stream>>>(d5c, dw2, db2, outc);
    }
}

// Round 10
// 1055.389 us; speedup vs baseline: 9.2142x; 1.0224x over previous
//
#include <hip/hip_runtime.h>
#include <hip/hip_bf16.h>
#include <math.h>

// R10: encoder+VQ numerics contract unchanged (bit-exact fp32 chain ci->kh->kw
// per output). Perf changes: conv2t = 2 ci-passes (23KB LDS, 7 blk/CU) with
// 16 co/wave (LDS reads 1:16 vs FMA); conv1/dec1 8 co/thread; dec2 3 co/thread.
// Decoder transposed convs remain bf16 MFMA implicit GEMM (R9).

__device__ __forceinline__ int rfl(int v) { return __builtin_amdgcn_readfirstlane(v); }

typedef __attribute__((ext_vector_type(8))) short s8v;
typedef __attribute__((ext_vector_type(4))) float f4v;

__device__ __forceinline__ ushort f2bf(float f) {
    __hip_bfloat16 h = __float2bfloat16(f);
    return *(ushort*)&h;
}

// -------- K1: conv 4x4 s2 p1, 3->32. Tile: 4 oh x 8 co per thread. (bit-exact)
__global__ __launch_bounds__(256) void k_conv1(const float* __restrict__ x, const float* __restrict__ w,
                                               const float* __restrict__ bias, float* __restrict__ out) {
    int t = blockIdx.x * 256 + threadIdx.x;
    int ow  = t & 127;
    int oh0 = ((t >> 7) & 31) * 4;
    int co0 = rfl((t >> 12) & 3) * 8;
    int b   = rfl(t >> 14);
    float acc[4][8] = {};
    for (int ci = 0; ci < 3; ci++) {
        const float* xp = x + (b * 3 + ci) * 65536;
        const float* wp = w + (co0 * 3 + ci) * 16;      // co stride 48
        #pragma unroll
        for (int r = 0; r < 10; r++) {
            int ih = oh0 * 2 - 1 + r;
            bool rok = (ih >= 0) && (ih < 256);
            int ihc = rok ? ih : 0;
            float v[4];
            #pragma unroll
            for (int c = 0; c < 4; c++) {
                int iw = ow * 2 - 1 + c;
                bool ok = rok && (iw >= 0) && (iw < 256);
                int iwc = iw < 0 ? 0 : (iw > 255 ? 255 : iw);
                float vv = xp[ihc * 256 + iwc];
                v[c] = ok ? vv : 0.f;
            }
            #pragma unroll
            for (int o = 0; o < 4; o++) {
                int kh = r - 2 * o;
                if (kh >= 0 && kh < 4) {
                    #pragma unroll
                    for (int cc = 0; cc < 8; cc++) {
                        const float* wc = wp + cc * 48 + kh * 4;
                        acc[o][cc] = __builtin_fmaf(v[0], wc[0], acc[o][cc]);
                        acc[o][cc] = __builtin_fmaf(v[1], wc[1], acc[o][cc]);
                        acc[o][cc] = __builtin_fmaf(v[2], wc[2], acc[o][cc]);
                        acc[o][cc] = __builtin_fmaf(v[3], wc[3], acc[o][cc]);
                    }
                }
            }
        }
    }
    #pragma unroll
    for (int cc = 0; cc < 8; cc++) {
        float bv = bias[co0 + cc];
        #pragma unroll
        for (int o = 0; o < 4; o++) {
            float v = acc[o][cc] + bv;
            out[((b * 32 + co0 + cc) * 128 + oh0 + o) * 128 + ow] = v > 0.f ? v : 0.f;
        }
    }
}

// -------- K2: conv 4x4 s2 p1, 32->64. 2 ci-passes (23KB LDS), 16 co per wave.
__global__ __launch_bounds__(256) void k_conv2t(const float* __restrict__ h1, const float* __restrict__ w,
                                                const float* __restrict__ bias, float* __restrict__ out) {
    __shared__ float P[16][18][2][10];   // 23,040 B -> ~7 blocks/CU
    int bx = blockIdx.x;
    int b  = bx >> 6;
    int ty = (bx >> 3) & 7, tx = bx & 7;
    int oh0 = ty * 8, ow0 = tx * 8;
    int tid = threadIdx.x;
    int lane = tid & 63;
    int dy = lane >> 3, dx = lane & 7;
    int co0 = rfl(tid >> 6) * 16;
    int oh = oh0 + dy, ow = ow0 + dx;
    float acc[16] = {};
    for (int pass = 0; pass < 2; pass++) {
        int cib = pass * 16;
        __syncthreads();
        for (int i = tid; i < 16 * 18 * 18; i += 256) {
            int cl = i / 324, rem = i - cl * 324;
            int r = rem / 18, c = rem - r * 18;
            int ih = oh0 * 2 - 1 + r, iw = ow0 * 2 - 1 + c;
            float v = 0.f;
            if (ih >= 0 && ih < 128 && iw >= 0 && iw < 128)
                v = h1[(b * 32 + cib + cl) * 16384 + ih * 128 + iw];
            P[cl][r][c & 1][c >> 1] = v;
        }
        __syncthreads();
        for (int cl = 0; cl < 16; cl++) {
            const float* wp = w + (co0 * 32 + cib + cl) * 16;   // co stride 512
            #pragma unroll
            for (int kh = 0; kh < 4; kh++) {
                int r = 2 * dy + kh;
                float v0 = P[cl][r][0][dx];       // kw0 (c=2dx)
                float v1 = P[cl][r][1][dx];       // kw1
                float v2 = P[cl][r][0][dx + 1];   // kw2
                float v3 = P[cl][r][1][dx + 1];   // kw3
                #pragma unroll
                for (int c = 0; c < 16; c++) {
                    const float* wc = wp + c * 512 + kh * 4;
                    acc[c] = __builtin_fmaf(v0, wc[0], acc[c]);
                    acc[c] = __builtin_fmaf(v1, wc[1], acc[c]);
                    acc[c] = __builtin_fmaf(v2, wc[2], acc[c]);
                    acc[c] = __builtin_fmaf(v3, wc[3], acc[c]);
                }
            }
        }
    }
    #pragma unroll
    for (int c = 0; c < 16; c++) {
        float v = acc[c] + bias[co0 + c];
        out[((b * 64 + co0 + c) * 64 + oh) * 64 + ow] = v > 0.f ? v : 0.f;
    }
}

// -------- K3: conv 1x1, 64->8 (bit-exact, unchanged).
__global__ __launch_bounds__(256) void k_conv3(const float* __restrict__ h2, const float* __restrict__ w,
                                               const float* __restrict__ bias, float* __restrict__ zf) {
    __shared__ float wl[8][64];
    __shared__ float bl[8];
    int tid = threadIdx.x;
    for (int i = tid; i < 512; i += 256) wl[i >> 6][i & 63] = w[i];
    if (tid < 8) bl[tid] = bias[tid];
    __syncthreads();
    int t = blockIdx.x * 256 + tid;
    int b = t >> 12, hw = t & 4095;
    float acc[8];
    for (int d = 0; d < 8; d++) acc[d] = 0.f;
    for (int ci = 0; ci < 64; ci++) {
        float v = h2[(b * 64 + ci) * 4096 + hw];
        for (int d = 0; d < 8; d++) acc[d] = __builtin_fmaf(v, wl[d][ci], acc[d]);
    }
    for (int d = 0; d < 8; d++)
        zf[(b * 8 + d) * 4096 + hw] = acc[d] + bl[d];
}

// -------- K4: VQ argmin (bit-exact, unchanged).
__global__ __launch_bounds__(256) void k_vq(const float* __restrict__ zf, const float* __restrict__ cb,
                                            int* __restrict__ idx, float* __restrict__ out_idx) {
    __shared__ float cbs[512][8];
    __shared__ float c2s[512];
    int tid = threadIdx.x;
    for (int i = tid; i < 4096; i += 256) cbs[i >> 3][i & 7] = cb[i];
    __syncthreads();
    for (int k = tid; k < 512; k += 256) {
        float s = 0.f;
        for (int d = 0; d < 8; d++) {
            float c = cbs[k][d];
            s = s + __fmul_rn(c, c);
        }
        c2s[k] = s;
    }
    __syncthreads();
    int n = blockIdx.x * 256 + tid;
    int b = n >> 12, hw = n & 4095;
    float zv[8], s1 = 0.f;
    for (int d = 0; d < 8; d++) {
        float z = zf[(b * 8 + d) * 4096 + hw];
        zv[d] = z;
        s1 = s1 + __fmul_rn(z, z);
    }
    float best = 3.4e38f; int bi = 0;
    for (int k = 0; k < 512; k++) {
        float dot = 0.f;
        for (int d = 0; d < 8; d++) dot = __builtin_fmaf(zv[d], cbs[k][d], dot);
        float a = s1 + c2s[k];
        float dist = a - __fmul_rn(2.0f, dot);
        if (dist < best) { best = dist; bi = k; }
    }
    idx[n] = bi;
    out_idx[n] = (float)bi;
}

// -------- K5: z_q + loss partials (unchanged).
__global__ __launch_bounds__(256) void k_zq(const int* __restrict__ idx, const float* __restrict__ cb,
                                            const float* __restrict__ zf, float* __restrict__ zq,
                                            double* __restrict__ partial) {
    __shared__ double red[256];
    int t = blockIdx.x * 256 + threadIdx.x;
    float q = cb[idx[t >> 3] * 8 + (t & 7)];
    zq[t] = q;
    double d = (double)zf[t] - (double)q;
    red[threadIdx.x] = d * d;
    __syncthreads();
    for (int s = 128; s > 0; s >>= 1) {
        if (threadIdx.x < s) red[threadIdx.x] += red[threadIdx.x + s];
        __syncthreads();
    }
    if (threadIdx.x == 0) partial[blockIdx.x] = red[0];
}

__global__ __launch_bounds__(256) void k_loss_fin(const double* __restrict__ partial, float* __restrict__ out_loss) {
    __shared__ double red[256];
    double s = 0.0;
    for (int i = threadIdx.x; i < 4096; i += 256) s += partial[i];
    red[threadIdx.x] = s;
    __syncthreads();
    for (int st = 128; st > 0; st >>= 1) {
        if (threadIdx.x < st) red[threadIdx.x] += red[threadIdx.x + st];
        __syncthreads();
    }
    if (threadIdx.x == 0)
        out_loss[0] = (float)(1.25 * red[0] / 1048576.0);
}

// -------- K7: conv 3x3 p1, 8->64. Tile: 4 oh x 8 co per thread.
__global__ __launch_bounds__(256) void k_dec1(const float* __restrict__ zq, const float* __restrict__ w,
                                              const float* __restrict__ bias, float* __restrict__ out) {
    int t = blockIdx.x * 256 + threadIdx.x;
    int ow  = t & 63;
    int oh0 = ((t >> 6) & 15) * 4;
    int co0 = rfl((t >> 10) & 7) * 8;
    int b   = rfl(t >> 13);
    float acc[4][8] = {};
    for (int ci = 0; ci < 8; ci++) {
        const float* ip = zq + (b * 8 + ci) * 4096;
        const float* wp = w + (co0 * 8 + ci) * 9;      // co stride 72
        #pragma unroll
        for (int r = 0; r < 6; r++) {
            int ih = oh0 - 1 + r;
            bool rok = (ih >= 0) && (ih < 64);
            int ihc = rok ? ih : 0;
            float v[3];
            #pragma unroll
            for (int c = 0; c < 3; c++) {
                int iw = ow - 1 + c;
                bool ok = rok && (iw >= 0) && (iw < 64);
                int iwc = iw < 0 ? 0 : (iw > 63 ? 63 : iw);
                float vv = ip[ihc * 64 + iwc];
                v[c] = ok ? vv : 0.f;
            }
            #pragma unroll
            for (int o = 0; o < 4; o++) {
                int kh = r - o;
                if (kh >= 0 && kh < 3) {
                    #pragma unroll
                    for (int cc = 0; cc < 8; cc++) {
                        const float* wc = wp + cc * 72 + kh * 3;
                        acc[o][cc] = __builtin_fmaf(v[0], wc[0], acc[o][cc]);
                        acc[o][cc] = __builtin_fmaf(v[1], wc[1], acc[o][cc]);
                        acc[o][cc] = __builtin_fmaf(v[2], wc[2], acc[o][cc]);
                    }
                }
            }
        }
    }
    #pragma unroll
    for (int cc = 0; cc < 8; cc++) {
        float bv = bias[co0 + cc];
        #pragma unroll
        for (int o = 0; o < 4; o++) {
            float v = acc[o][cc] + bv;
            out[((b * 64 + co0 + cc) * 64 + oh0 + o) * 64 + ow] = v > 0.f ? v : 0.f;
        }
    }
}

// -------- Weight prep for MFMA dect (unchanged).
template <int CI, int CO>
__global__ __launch_bounds__(256) void k_wprep(const float* __restrict__ w, ushort* __restrict__ Wf) {
    constexpr int NT = CO / 16;
    int t = blockIdx.x * 256 + threadIdx.x;
    if (t >= 4 * NT * 8 * 64) return;
    int lane = t & 63;
    int kt = (t >> 6) & 7;
    int nt = (t >> 9) % NT;
    int q  = t / (512 * NT);
    int py = q >> 1, px = q & 1;
    int n = nt * 16 + (lane & 15);
    int cb = (kt & 1) * 32 + (lane >> 4) * 8;
    int tap = kt >> 1, dy = tap >> 1, dx = tap & 1;
    #pragma unroll
    for (int jj = 0; jj < 8; jj++) {
        int ci = cb + jj;
        float v = w[((n * CI + ci) * 4 + (py + 2 * dy)) * 4 + (px + 2 * dx)];
        Wf[(((q * NT + nt) * 8 + kt) * 64 + lane) * 8 + jj] = f2bf(v);
    }
}

// -------- K8/K9: transposed conv via bf16 MFMA (unchanged).
template <int CI, int CO, int HIN>
__global__ __launch_bounds__(256) void k_dect_mfma(const float* __restrict__ in, const ushort* __restrict__ Wf,
                                                   const float* __restrict__ bias, float* __restrict__ out) {
    constexpr int NT = CO / 16;
    constexpr int TILES = HIN / 16;
    constexpr int HOUT = 2 * HIN;
    __shared__ alignas(16) ushort L[18 * 18 * 72];
    int blk = blockIdx.x;
    int b = blk / (TILES * TILES);
    int tile = blk - b * (TILES * TILES);
    int i0 = (tile / TILES) * 16, j0 = (tile % TILES) * 16;
    const float* ip = in + (size_t)b * CI * HIN * HIN;
    for (int e = threadIdx.x; e < 18 * 18 * CI; e += 256) {
        int ci = e / 324; int rem = e - ci * 324;
        int row = rem / 18; int col = rem - row * 18;
        int ih = i0 - 1 + row, iw = j0 - 1 + col;
        float v = 0.f;
        if (ih >= 0 && ih < HIN && iw >= 0 && iw < HIN)
            v = ip[(size_t)ci * (HIN * HIN) + ih * HIN + iw];
        L[(row * 18 + col) * 72 + ci] = f2bf(v);
    }
    __syncthreads();
    int wv = threadIdx.x >> 6;
    int lane = threadIdx.x & 63;
    int py = wv >> 1, px = wv & 1;
    int m = lane & 15, quad = lane >> 4;
    const ushort* wq = Wf + (size_t)wv * NT * 8 * 64 * 8;
    for (int il = 0; il < 16; il++) {
        s8v a[8];
        #pragma unroll
        for (int kt = 0; kt < 8; kt++) {
            int tap = kt >> 1, dy = tap >> 1, dx = tap & 1;
            int r = il + py + dy, cl = m + px + dx;
            a[kt] = *(s8v*)&L[(r * 18 + cl) * 72 + (kt & 1) * 32 + quad * 8];
        }
        #pragma unroll
        for (int nt = 0; nt < NT; nt++) {
            f4v acc = {0.f, 0.f, 0.f, 0.f};
            #pragma unroll
            for (int kt = 0; kt < 8; kt++) {
                s8v bf = *(const s8v*)&wq[((nt * 8 + kt) * 64 + lane) * 8];
                acc = __builtin_amdgcn_mfma_f32_16x16x32_bf16(a[kt], bf, acc, 0, 0, 0);
            }
            int co = nt * 16 + m;
            float bv = bias[co];
            int y = 2 * (i0 + il) + py;
            #pragma unroll
            for (int reg = 0; reg < 4; reg++) {
                int jD = j0 + quad * 4 + reg;
                int xx = 2 * jD + px;
                float v = acc[reg] + bv;
                out[((size_t)(b * CO + co) * HOUT + y) * HOUT + xx] = v > 0.f ? v : 0.f;
            }
        }
    }
}

// -------- K10: conv 3x3 p1, 32->3, sigmoid. 4 y x all-3 co per thread.
__global__ __launch_bounds__(256) void k_dec2(const float* __restrict__ in, const float* __restrict__ w,
                                              const float* __restrict__ bias, float* __restrict__ out) {
    int t = blockIdx.x * 256 + threadIdx.x;
    int x  = t & 255;
    int y0 = ((t >> 8) & 63) * 4;
    int b  = rfl(t >> 14);
    float acc[4][3] = {};
    for (int ci = 0; ci < 32; ci++) {
        const float* ip = in + (size_t)(b * 32 + ci) * 65536;
        const float* wp = w + ci * 9;            // co stride 288
        #pragma unroll
        for (int rr = 0; rr < 6; rr++) {
            int ih = y0 - 1 + rr;
            bool rok = (ih >= 0) && (ih < 256);
            int ihc = rok ? ih : 0;
            float v[3];
            #pragma unroll
            for (int c = 0; c < 3; c++) {
                int iw = x - 1 + c;
                bool ok = rok && (iw >= 0) && (iw < 256);
                int iwc = iw < 0 ? 0 : (iw > 255 ? 255 : iw);
                float vv = ip[ihc * 256 + iwc];
                v[c] = ok ? vv : 0.f;
            }
            #pragma unroll
            for (int o = 0; o < 4; o++) {
                int kh = rr - o;
                if (kh >= 0 && kh < 3) {
                    #pragma unroll
                    for (int co = 0; co < 3; co++) {
                        const float* wc = wp + co * 288 + kh * 3;
                        acc[o][co] = __builtin_fmaf(v[0], wc[0], acc[o][co]);
                        acc[o][co] = __builtin_fmaf(v[1], wc[1], acc[o][co]);
                        acc[o][co] = __builtin_fmaf(v[2], wc[2], acc[o][co]);
                    }
                }
            }
        }
    }
    #pragma unroll
    for (int co = 0; co < 3; co++) {
        float bv = bias[co];
        #pragma unroll
        for (int o = 0; o < 4; o++) {
            float v = acc[o][co] + bv;
            out[((size_t)(b * 3 + co) * 256 + y0 + o) * 256 + x] = 1.0f / (1.0f + expf(-v));
        }
    }
}

extern "C" void kernel_launch(void* const* d_in, const int* in_sizes, int n_in,
                              void* d_out, int out_size, void* d_ws, size_t ws_size,
                              hipStream_t stream) {
    const float* x    = (const float*)d_in[0];
    const float* ew1  = (const float*)d_in[1];
    const float* eb1  = (const float*)d_in[2];
    const float* ew2  = (const float*)d_in[3];
    const float* eb2  = (const float*)d_in[4];
    const float* ew3  = (const float*)d_in[5];
    const float* eb3  = (const float*)d_in[6];
    const float* cb   = (const float*)d_in[7];
    const float* dw1  = (const float*)d_in[8];
    const float* db1  = (const float*)d_in[9];
    const float* dtw1 = (const float*)d_in[10];
    const float* dtb1 = (const float*)d_in[11];
    const float* dtw2 = (const float*)d_in[12];
    const float* dtb2 = (const float*)d_in[13];
    const float* dw2  = (const float*)d_in[14];
    const float* db2  = (const float*)d_in[15];

    char* ws = (char*)d_ws;
    float*  z32  = (float*) (ws);               //  4,194,304 B
    float*  zq   = (float*) (ws + 4194304);     //  4,194,304 B
    int*    idx  = (int*)   (ws + 8388608);     //    524,288 B
    double* part = (double*)(ws + 8912896);     //     32,768 B
    ushort* Wf1  = (ushort*)(ws + 8945664);     //    131,072 B
    ushort* Wf2  = (ushort*)(ws + 9076736);     //     65,536 B
    char* region = ws + 9142272;

    size_t fixed = 9142272;
    size_t avail = (ws_size > fixed) ? ws_size - fixed : 0;
    int ce = 32, cd = 32;
    while (ce > 1 && (size_t)ce * 3145728ull > avail) ce >>= 1;   // h1(2MB)+h2(1MB)
    while (cd > 1 && (size_t)cd * 13631488ull > avail) cd >>= 1;  // d3(1)+d4(4)+d5(8MB)

    float* h1c = (float*)region;                                  // (ce,32,128,128)
    float* h2c = (float*)(region + (size_t)ce * 2097152ull);      // (ce,64,64,64)
    float* d3c = (float*) region;                                 // (cd,64,64,64)
    float* d4c = (float*) (region + (size_t)cd * 1048576ull);     // (cd,64,128,128)
    float* d5c = (float*) (region + (size_t)cd * 5242880ull);     // (cd,32,256,256)

    float* out      = (float*)d_out;
    float* out_loss = out + 6291456;
    float* out_idx  = out + 6291457;

    for (int c = 0; c < 32 / ce; c++) {
        const float* xc = x + (size_t)c * ce * 196608ull;
        k_conv1<<<ce * 64, 256, 0, stream>>>(xc, ew1, eb1, h1c);
        k_conv2t<<<ce * 64, 256, 0, stream>>>(h1c, ew2, eb2, h2c);
        k_conv3<<<ce * 16,  256, 0, stream>>>(h2c, ew3, eb3, z32 + (size_t)c * ce * 32768ull);
    }

    k_vq<<<512, 256, 0, stream>>>(z32, cb, idx, out_idx);
    k_zq<<<4096, 256, 0, stream>>>(idx, cb, z32, zq, part);
    k_loss_fin<<<1, 256, 0, stream>>>(part, out_loss);

    k_wprep<64, 64><<<32, 256, 0, stream>>>(dtw1, Wf1);
    k_wprep<64, 32><<<16, 256, 0, stream>>>(dtw2, Wf2);

    for (int c = 0; c < 32 / cd; c++) {
        const float* zqc = zq + (size_t)c * cd * 32768ull;
        float* outc = out + (size_t)c * cd * 196608ull;
        k_dec1<<<cd * 32, 256, 0, stream>>>(zqc, dw1, db1, d3c);
        k_dect_mfma<64, 64, 64 ><<<cd * 16, 256, 0, stream>>>(d3c, Wf1, dtb1, d4c);
        k_dect_mfma<64, 32, 128><<<cd * 64, 256, 0, stream>>>(d4c, Wf2, dtb2, d5c);
        k_dec2<<<cd * 64, 256, 0, stream>>>(d5c, dw2, db2, outc);
    }
}

// Round 12
// 982.681 us; speedup vs baseline: 9.8960x; 1.0740x over previous
//
#include <hip/hip_runtime.h>
#include <hip/hip_bf16.h>
#include <math.h>

// R12: R11 resubmit with hardening — cc loop unrolled, scalar accumulators
// (no dynamically-indexed private array -> no scratch). conv2t = R9 inner loop
// (4-co chunks) + 2-pass ci-split LDS (23KB). Per-output FMA chain stays
// ci->kh->kw (bit-exact, matches np argmin). Everything else = R10/R11.

__device__ __forceinline__ int rfl(int v) { return __builtin_amdgcn_readfirstlane(v); }

typedef __attribute__((ext_vector_type(8))) short s8v;
typedef __attribute__((ext_vector_type(4))) float f4v;

__device__ __forceinline__ ushort f2bf(float f) {
    __hip_bfloat16 h = __float2bfloat16(f);
    return *(ushort*)&h;
}

// -------- K1: conv 4x4 s2 p1, 3->32. Tile: 4 oh x 8 co per thread. (bit-exact)
__global__ __launch_bounds__(256) void k_conv1(const float* __restrict__ x, const float* __restrict__ w,
                                               const float* __restrict__ bias, float* __restrict__ out) {
    int t = blockIdx.x * 256 + threadIdx.x;
    int ow  = t & 127;
    int oh0 = ((t >> 7) & 31) * 4;
    int co0 = rfl((t >> 12) & 3) * 8;
    int b   = rfl(t >> 14);
    float acc[4][8] = {};
    for (int ci = 0; ci < 3; ci++) {
        const float* xp = x + (b * 3 + ci) * 65536;
        const float* wp = w + (co0 * 3 + ci) * 16;      // co stride 48
        #pragma unroll
        for (int r = 0; r < 10; r++) {
            int ih = oh0 * 2 - 1 + r;
            bool rok = (ih >= 0) && (ih < 256);
            int ihc = rok ? ih : 0;
            float v[4];
            #pragma unroll
            for (int c = 0; c < 4; c++) {
                int iw = ow * 2 - 1 + c;
                bool ok = rok && (iw >= 0) && (iw < 256);
                int iwc = iw < 0 ? 0 : (iw > 255 ? 255 : iw);
                float vv = xp[ihc * 256 + iwc];
                v[c] = ok ? vv : 0.f;
            }
            #pragma unroll
            for (int o = 0; o < 4; o++) {
                int kh = r - 2 * o;
                if (kh >= 0 && kh < 4) {
                    #pragma unroll
                    for (int cc = 0; cc < 8; cc++) {
                        const float* wc = wp + cc * 48 + kh * 4;
                        acc[o][cc] = __builtin_fmaf(v[0], wc[0], acc[o][cc]);
                        acc[o][cc] = __builtin_fmaf(v[1], wc[1], acc[o][cc]);
                        acc[o][cc] = __builtin_fmaf(v[2], wc[2], acc[o][cc]);
                        acc[o][cc] = __builtin_fmaf(v[3], wc[3], acc[o][cc]);
                    }
                }
            }
        }
    }
    #pragma unroll
    for (int cc = 0; cc < 8; cc++) {
        float bv = bias[co0 + cc];
        #pragma unroll
        for (int o = 0; o < 4; o++) {
            float v = acc[o][cc] + bv;
            out[((b * 32 + co0 + cc) * 128 + oh0 + o) * 128 + ow] = v > 0.f ? v : 0.f;
        }
    }
}

// -------- K2: conv 4x4 s2 p1, 32->64. 2 ci-passes (23KB LDS), 4-co-chunk inner loop.
__global__ __launch_bounds__(256) void k_conv2t(const float* __restrict__ h1, const float* __restrict__ w,
                                                const float* __restrict__ bias, float* __restrict__ out) {
    __shared__ float P[16][18][2][10];   // 23,040 B
    int bx = blockIdx.x;
    int b  = bx >> 6;
    int ty = (bx >> 3) & 7, tx = bx & 7;
    int oh0 = ty * 8, ow0 = tx * 8;
    int tid = threadIdx.x;
    int lane = tid & 63;
    int dy = lane >> 3, dx = lane & 7;
    int co_base = rfl(tid >> 6) * 16;
    int oh = oh0 + dy, ow = ow0 + dx;
    // 16 scalar accumulators (4 co-chunks x 4 co), persist across ci-passes
    float s00 = 0.f, s01 = 0.f, s02 = 0.f, s03 = 0.f;
    float s10 = 0.f, s11 = 0.f, s12 = 0.f, s13 = 0.f;
    float s20 = 0.f, s21 = 0.f, s22 = 0.f, s23 = 0.f;
    float s30 = 0.f, s31 = 0.f, s32 = 0.f, s33 = 0.f;

    #pragma unroll
    for (int pass = 0; pass < 2; pass++) {
        int cib = pass * 16;
        __syncthreads();
        for (int i = tid; i < 16 * 18 * 18; i += 256) {
            int cl = i / 324, rem = i - cl * 324;
            int r = rem / 18, c = rem - r * 18;
            int ih = oh0 * 2 - 1 + r, iw = ow0 * 2 - 1 + c;
            float v = 0.f;
            if (ih >= 0 && ih < 128 && iw >= 0 && iw < 128)
                v = h1[(b * 32 + cib + cl) * 16384 + ih * 128 + iw];
            P[cl][r][c & 1][c >> 1] = v;
        }
        __syncthreads();
        #pragma unroll
        for (int cc = 0; cc < 4; cc++) {
            int co0 = co_base + cc * 4;
            float a0 = (cc == 0) ? s00 : (cc == 1) ? s10 : (cc == 2) ? s20 : s30;
            float a1 = (cc == 0) ? s01 : (cc == 1) ? s11 : (cc == 2) ? s21 : s31;
            float a2 = (cc == 0) ? s02 : (cc == 1) ? s12 : (cc == 2) ? s22 : s32;
            float a3 = (cc == 0) ? s03 : (cc == 1) ? s13 : (cc == 2) ? s23 : s33;
            for (int cl = 0; cl < 16; cl++) {
                const float* wp0 = w + ((co0 + 0) * 32 + cib + cl) * 16;
                const float* wp1 = w + ((co0 + 1) * 32 + cib + cl) * 16;
                const float* wp2 = w + ((co0 + 2) * 32 + cib + cl) * 16;
                const float* wp3 = w + ((co0 + 3) * 32 + cib + cl) * 16;
                #pragma unroll
                for (int kh = 0; kh < 4; kh++) {
                    int r = 2 * dy + kh;
                    float v0 = P[cl][r][0][dx];
                    float v1 = P[cl][r][1][dx];
                    float v2 = P[cl][r][0][dx + 1];
                    float v3 = P[cl][r][1][dx + 1];
                    a0 = __builtin_fmaf(v0, wp0[kh*4+0], a0); a0 = __builtin_fmaf(v1, wp0[kh*4+1], a0);
                    a0 = __builtin_fmaf(v2, wp0[kh*4+2], a0); a0 = __builtin_fmaf(v3, wp0[kh*4+3], a0);
                    a1 = __builtin_fmaf(v0, wp1[kh*4+0], a1); a1 = __builtin_fmaf(v1, wp1[kh*4+1], a1);
                    a1 = __builtin_fmaf(v2, wp1[kh*4+2], a1); a1 = __builtin_fmaf(v3, wp1[kh*4+3], a1);
                    a2 = __builtin_fmaf(v0, wp2[kh*4+0], a2); a2 = __builtin_fmaf(v1, wp2[kh*4+1], a2);
                    a2 = __builtin_fmaf(v2, wp2[kh*4+2], a2); a2 = __builtin_fmaf(v3, wp2[kh*4+3], a2);
                    a3 = __builtin_fmaf(v0, wp3[kh*4+0], a3); a3 = __builtin_fmaf(v1, wp3[kh*4+1], a3);
                    a3 = __builtin_fmaf(v2, wp3[kh*4+2], a3); a3 = __builtin_fmaf(v3, wp3[kh*4+3], a3);
                }
            }
            if (cc == 0)      { s00 = a0; s01 = a1; s02 = a2; s03 = a3; }
            else if (cc == 1) { s10 = a0; s11 = a1; s12 = a2; s13 = a3; }
            else if (cc == 2) { s20 = a0; s21 = a1; s22 = a2; s23 = a3; }
            else              { s30 = a0; s31 = a1; s32 = a2; s33 = a3; }
        }
    }
    float r0, r1, r2, r3;
    #pragma unroll
    for (int cc = 0; cc < 4; cc++) {
        int co0 = co_base + cc * 4;
        if (cc == 0)      { r0 = s00; r1 = s01; r2 = s02; r3 = s03; }
        else if (cc == 1) { r0 = s10; r1 = s11; r2 = s12; r3 = s13; }
        else if (cc == 2) { r0 = s20; r1 = s21; r2 = s22; r3 = s23; }
        else              { r0 = s30; r1 = s31; r2 = s32; r3 = s33; }
        float v0 = r0 + bias[co0 + 0], v1 = r1 + bias[co0 + 1];
        float v2 = r2 + bias[co0 + 2], v3 = r3 + bias[co0 + 3];
        out[((b * 64 + co0 + 0) * 64 + oh) * 64 + ow] = v0 > 0.f ? v0 : 0.f;
        out[((b * 64 + co0 + 1) * 64 + oh) * 64 + ow] = v1 > 0.f ? v1 : 0.f;
        out[((b * 64 + co0 + 2) * 64 + oh) * 64 + ow] = v2 > 0.f ? v2 : 0.f;
        out[((b * 64 + co0 + 3) * 64 + oh) * 64 + ow] = v3 > 0.f ? v3 : 0.f;
    }
}

// -------- K3: conv 1x1, 64->8 (bit-exact, unchanged).
__global__ __launch_bounds__(256) void k_conv3(const float* __restrict__ h2, const float* __restrict__ w,
                                               const float* __restrict__ bias, float* __restrict__ zf) {
    __shared__ float wl[8][64];
    __shared__ float bl[8];
    int tid = threadIdx.x;
    for (int i = tid; i < 512; i += 256) wl[i >> 6][i & 63] = w[i];
    if (tid < 8) bl[tid] = bias[tid];
    __syncthreads();
    int t = blockIdx.x * 256 + tid;
    int b = t >> 12, hw = t & 4095;
    float acc[8];
    for (int d = 0; d < 8; d++) acc[d] = 0.f;
    for (int ci = 0; ci < 64; ci++) {
        float v = h2[(b * 64 + ci) * 4096 + hw];
        for (int d = 0; d < 8; d++) acc[d] = __builtin_fmaf(v, wl[d][ci], acc[d]);
    }
    for (int d = 0; d < 8; d++)
        zf[(b * 8 + d) * 4096 + hw] = acc[d] + bl[d];
}

// -------- K4: VQ argmin (bit-exact, unchanged).
__global__ __launch_bounds__(256) void k_vq(const float* __restrict__ zf, const float* __restrict__ cb,
                                            int* __restrict__ idx, float* __restrict__ out_idx) {
    __shared__ float cbs[512][8];
    __shared__ float c2s[512];
    int tid = threadIdx.x;
    for (int i = tid; i < 4096; i += 256) cbs[i >> 3][i & 7] = cb[i];
    __syncthreads();
    for (int k = tid; k < 512; k += 256) {
        float s = 0.f;
        for (int d = 0; d < 8; d++) {
            float c = cbs[k][d];
            s = s + __fmul_rn(c, c);
        }
        c2s[k] = s;
    }
    __syncthreads();
    int n = blockIdx.x * 256 + tid;
    int b = n >> 12, hw = n & 4095;
    float zv[8], s1 = 0.f;
    for (int d = 0; d < 8; d++) {
        float z = zf[(b * 8 + d) * 4096 + hw];
        zv[d] = z;
        s1 = s1 + __fmul_rn(z, z);
    }
    float best = 3.4e38f; int bi = 0;
    for (int k = 0; k < 512; k++) {
        float dot = 0.f;
        for (int d = 0; d < 8; d++) dot = __builtin_fmaf(zv[d], cbs[k][d], dot);
        float a = s1 + c2s[k];
        float dist = a - __fmul_rn(2.0f, dot);
        if (dist < best) { best = dist; bi = k; }
    }
    idx[n] = bi;
    out_idx[n] = (float)bi;
}

// -------- K5: z_q + loss partials (unchanged).
__global__ __launch_bounds__(256) void k_zq(const int* __restrict__ idx, const float* __restrict__ cb,
                                            const float* __restrict__ zf, float* __restrict__ zq,
                                            double* __restrict__ partial) {
    __shared__ double red[256];
    int t = blockIdx.x * 256 + threadIdx.x;
    float q = cb[idx[t >> 3] * 8 + (t & 7)];
    zq[t] = q;
    double d = (double)zf[t] - (double)q;
    red[threadIdx.x] = d * d;
    __syncthreads();
    for (int s = 128; s > 0; s >>= 1) {
        if (threadIdx.x < s) red[threadIdx.x] += red[threadIdx.x + s];
        __syncthreads();
    }
    if (threadIdx.x == 0) partial[blockIdx.x] = red[0];
}

__global__ __launch_bounds__(256) void k_loss_fin(const double* __restrict__ partial, float* __restrict__ out_loss) {
    __shared__ double red[256];
    double s = 0.0;
    for (int i = threadIdx.x; i < 4096; i += 256) s += partial[i];
    red[threadIdx.x] = s;
    __syncthreads();
    for (int st = 128; st > 0; st >>= 1) {
        if (threadIdx.x < st) red[threadIdx.x] += red[threadIdx.x + st];
        __syncthreads();
    }
    if (threadIdx.x == 0)
        out_loss[0] = (float)(1.25 * red[0] / 1048576.0);
}

// -------- K7: conv 3x3 p1, 8->64. Tile: 4 oh x 8 co per thread (unchanged).
__global__ __launch_bounds__(256) void k_dec1(const float* __restrict__ zq, const float* __restrict__ w,
                                              const float* __restrict__ bias, float* __restrict__ out) {
    int t = blockIdx.x * 256 + threadIdx.x;
    int ow  = t & 63;
    int oh0 = ((t >> 6) & 15) * 4;
    int co0 = rfl((t >> 10) & 7) * 8;
    int b   = rfl(t >> 13);
    float acc[4][8] = {};
    for (int ci = 0; ci < 8; ci++) {
        const float* ip = zq + (b * 8 + ci) * 4096;
        const float* wp = w + (co0 * 8 + ci) * 9;      // co stride 72
        #pragma unroll
        for (int r = 0; r < 6; r++) {
            int ih = oh0 - 1 + r;
            bool rok = (ih >= 0) && (ih < 64);
            int ihc = rok ? ih : 0;
            float v[3];
            #pragma unroll
            for (int c = 0; c < 3; c++) {
                int iw = ow - 1 + c;
                bool ok = rok && (iw >= 0) && (iw < 64);
                int iwc = iw < 0 ? 0 : (iw > 63 ? 63 : iw);
                float vv = ip[ihc * 64 + iwc];
                v[c] = ok ? vv : 0.f;
            }
            #pragma unroll
            for (int o = 0; o < 4; o++) {
                int kh = r - o;
                if (kh >= 0 && kh < 3) {
                    #pragma unroll
                    for (int cc = 0; cc < 8; cc++) {
                        const float* wc = wp + cc * 72 + kh * 3;
                        acc[o][cc] = __builtin_fmaf(v[0], wc[0], acc[o][cc]);
                        acc[o][cc] = __builtin_fmaf(v[1], wc[1], acc[o][cc]);
                        acc[o][cc] = __builtin_fmaf(v[2], wc[2], acc[o][cc]);
                    }
                }
            }
        }
    }
    #pragma unroll
    for (int cc = 0; cc < 8; cc++) {
        float bv = bias[co0 + cc];
        #pragma unroll
        for (int o = 0; o < 4; o++) {
            float v = acc[o][cc] + bv;
            out[((b * 64 + co0 + cc) * 64 + oh0 + o) * 64 + ow] = v > 0.f ? v : 0.f;
        }
    }
}

// -------- Weight prep for MFMA dect (unchanged).
template <int CI, int CO>
__global__ __launch_bounds__(256) void k_wprep(const float* __restrict__ w, ushort* __restrict__ Wf) {
    constexpr int NT = CO / 16;
    int t = blockIdx.x * 256 + threadIdx.x;
    if (t >= 4 * NT * 8 * 64) return;
    int lane = t & 63;
    int kt = (t >> 6) & 7;
    int nt = (t >> 9) % NT;
    int q  = t / (512 * NT);
    int py = q >> 1, px = q & 1;
    int n = nt * 16 + (lane & 15);
    int cb = (kt & 1) * 32 + (lane >> 4) * 8;
    int tap = kt >> 1, dy = tap >> 1, dx = tap & 1;
    #pragma unroll
    for (int jj = 0; jj < 8; jj++) {
        int ci = cb + jj;
        float v = w[((n * CI + ci) * 4 + (py + 2 * dy)) * 4 + (px + 2 * dx)];
        Wf[(((q * NT + nt) * 8 + kt) * 64 + lane) * 8 + jj] = f2bf(v);
    }
}

// -------- K8/K9: transposed conv via bf16 MFMA (unchanged).
template <int CI, int CO, int HIN>
__global__ __launch_bounds__(256) void k_dect_mfma(const float* __restrict__ in, const ushort* __restrict__ Wf,
                                                   const float* __restrict__ bias, float* __restrict__ out) {
    constexpr int NT = CO / 16;
    constexpr int TILES = HIN / 16;
    constexpr int HOUT = 2 * HIN;
    __shared__ alignas(16) ushort L[18 * 18 * 72];
    int blk = blockIdx.x;
    int b = blk / (TILES * TILES);
    int tile = blk - b * (TILES * TILES);
    int i0 = (tile / TILES) * 16, j0 = (tile % TILES) * 16;
    const float* ip = in + (size_t)b * CI * HIN * HIN;
    for (int e = threadIdx.x; e < 18 * 18 * CI; e += 256) {
        int ci = e / 324; int rem = e - ci * 324;
        int row = rem / 18; int col = rem - row * 18;
        int ih = i0 - 1 + row, iw = j0 - 1 + col;
        float v = 0.f;
        if (ih >= 0 && ih < HIN && iw >= 0 && iw < HIN)
            v = ip[(size_t)ci * (HIN * HIN) + ih * HIN + iw];
        L[(row * 18 + col) * 72 + ci] = f2bf(v);
    }
    __syncthreads();
    int wv = threadIdx.x >> 6;
    int lane = threadIdx.x & 63;
    int py = wv >> 1, px = wv & 1;
    int m = lane & 15, quad = lane >> 4;
    const ushort* wq = Wf + (size_t)wv * NT * 8 * 64 * 8;
    for (int il = 0; il < 16; il++) {
        s8v a[8];
        #pragma unroll
        for (int kt = 0; kt < 8; kt++) {
            int tap = kt >> 1, dy = tap >> 1, dx = tap & 1;
            int r = il + py + dy, cl = m + px + dx;
            a[kt] = *(s8v*)&L[(r * 18 + cl) * 72 + (kt & 1) * 32 + quad * 8];
        }
        #pragma unroll
        for (int nt = 0; nt < NT; nt++) {
            f4v acc = {0.f, 0.f, 0.f, 0.f};
            #pragma unroll
            for (int kt = 0; kt < 8; kt++) {
                s8v bf = *(const s8v*)&wq[((nt * 8 + kt) * 64 + lane) * 8];
                acc = __builtin_amdgcn_mfma_f32_16x16x32_bf16(a[kt], bf, acc, 0, 0, 0);
            }
            int co = nt * 16 + m;
            float bv = bias[co];
            int y = 2 * (i0 + il) + py;
            #pragma unroll
            for (int reg = 0; reg < 4; reg++) {
                int jD = j0 + quad * 4 + reg;
                int xx = 2 * jD + px;
                float v = acc[reg] + bv;
                out[((size_t)(b * CO + co) * HOUT + y) * HOUT + xx] = v > 0.f ? v : 0.f;
            }
        }
    }
}

// -------- K10: conv 3x3 p1, 32->3, sigmoid. 4 y x all-3 co per thread (unchanged).
__global__ __launch_bounds__(256) void k_dec2(const float* __restrict__ in, const float* __restrict__ w,
                                              const float* __restrict__ bias, float* __restrict__ out) {
    int t = blockIdx.x * 256 + threadIdx.x;
    int x  = t & 255;
    int y0 = ((t >> 8) & 63) * 4;
    int b  = rfl(t >> 14);
    float acc[4][3] = {};
    for (int ci = 0; ci < 32; ci++) {
        const float* ip = in + (size_t)(b * 32 + ci) * 65536;
        const float* wp = w + ci * 9;            // co stride 288
        #pragma unroll
        for (int rr = 0; rr < 6; rr++) {
            int ih = y0 - 1 + rr;
            bool rok = (ih >= 0) && (ih < 256);
            int ihc = rok ? ih : 0;
            float v[3];
            #pragma unroll
            for (int c = 0; c < 3; c++) {
                int iw = x - 1 + c;
                bool ok = rok && (iw >= 0) && (iw < 256);
                int iwc = iw < 0 ? 0 : (iw > 255 ? 255 : iw);
                float vv = ip[ihc * 256 + iwc];
                v[c] = ok ? vv : 0.f;
            }
            #pragma unroll
            for (int o = 0; o < 4; o++) {
                int kh = rr - o;
                if (kh >= 0 && kh < 3) {
                    #pragma unroll
                    for (int co = 0; co < 3; co++) {
                        const float* wc = wp + co * 288 + kh * 3;
                        acc[o][co] = __builtin_fmaf(v[0], wc[0], acc[o][co]);
                        acc[o][co] = __builtin_fmaf(v[1], wc[1], acc[o][co]);
                        acc[o][co] = __builtin_fmaf(v[2], wc[2], acc[o][co]);
                    }
                }
            }
        }
    }
    #pragma unroll
    for (int co = 0; co < 3; co++) {
        float bv = bias[co];
        #pragma unroll
        for (int o = 0; o < 4; o++) {
            float v = acc[o][co] + bv;
            out[((size_t)(b * 3 + co) * 256 + y0 + o) * 256 + x] = 1.0f / (1.0f + expf(-v));
        }
    }
}

extern "C" void kernel_launch(void* const* d_in, const int* in_sizes, int n_in,
                              void* d_out, int out_size, void* d_ws, size_t ws_size,
                              hipStream_t stream) {
    const float* x    = (const float*)d_in[0];
    const float* ew1  = (const float*)d_in[1];
    const float* eb1  = (const float*)d_in[2];
    const float* ew2  = (const float*)d_in[3];
    const float* eb2  = (const float*)d_in[4];
    const float* ew3  = (const float*)d_in[5];
    const float* eb3  = (const float*)d_in[6];
    const float* cb   = (const float*)d_in[7];
    const float* dw1  = (const float*)d_in[8];
    const float* db1  = (const float*)d_in[9];
    const float* dtw1 = (const float*)d_in[10];
    const float* dtb1 = (const float*)d_in[11];
    const float* dtw2 = (const float*)d_in[12];
    const float* dtb2 = (const float*)d_in[13];
    const float* dw2  = (const float*)d_in[14];
    const float* db2  = (const float*)d_in[15];

    char* ws = (char*)d_ws;
    float*  z32  = (float*) (ws);               //  4,194,304 B
    float*  zq   = (float*) (ws + 4194304);     //  4,194,304 B
    int*    idx  = (int*)   (ws + 8388608);     //    524,288 B
    double* part = (double*)(ws + 8912896);     //     32,768 B
    ushort* Wf1  = (ushort*)(ws + 8945664);     //    131,072 B
    ushort* Wf2  = (ushort*)(ws + 9076736);     //     65,536 B
    char* region = ws + 9142272;

    size_t fixed = 9142272;
    size_t avail = (ws_size > fixed) ? ws_size - fixed : 0;
    int ce = 32, cd = 32;
    while (ce > 1 && (size_t)ce * 3145728ull > avail) ce >>= 1;   // h1(2MB)+h2(1MB)
    while (cd > 1 && (size_t)cd * 13631488ull > avail) cd >>= 1;  // d3(1)+d4(4)+d5(8MB)

    float* h1c = (float*)region;                                  // (ce,32,128,128)
    float* h2c = (float*)(region + (size_t)ce * 2097152ull);      // (ce,64,64,64)
    float* d3c = (float*) region;                                 // (cd,64,64,64)
    float* d4c = (float*) (region + (size_t)cd * 1048576ull);     // (cd,64,128,128)
    float* d5c = (float*) (region + (size_t)cd * 5242880ull);     // (cd,32,256,256)

    float* out      = (float*)d_out;
    float* out_loss = out + 6291456;
    float* out_idx  = out + 6291457;

    for (int c = 0; c < 32 / ce; c++) {
        const float* xc = x + (size_t)c * ce * 196608ull;
        k_conv1<<<ce * 64, 256, 0, stream>>>(xc, ew1, eb1, h1c);
        k_conv2t<<<ce * 64, 256, 0, stream>>>(h1c, ew2, eb2, h2c);
        k_conv3<<<ce * 16,  256, 0, stream>>>(h2c, ew3, eb3, z32 + (size_t)c * ce * 32768ull);
    }

    k_vq<<<512, 256, 0, stream>>>(z32, cb, idx, out_idx);
    k_zq<<<4096, 256, 0, stream>>>(idx, cb, z32, zq, part);
    k_loss_fin<<<1, 256, 0, stream>>>(part, out_loss);

    k_wprep<64, 64><<<32, 256, 0, stream>>>(dtw1, Wf1);
    k_wprep<64, 32><<<16, 256, 0, stream>>>(dtw2, Wf2);

    for (int c = 0; c < 32 / cd; c++) {
        const float* zqc = zq + (size_t)c * cd * 32768ull;
        float* outc = out + (size_t)c * cd * 196608ull;
        k_dec1<<<cd * 32, 256, 0, stream>>>(zqc, dw1, db1, d3c);
        k_dect_mfma<64, 64, 64 ><<<cd * 16, 256, 0, stream>>>(d3c, Wf1, dtb1, d4c);
        k_dect_mfma<64, 32, 128><<<cd * 64, 256, 0, stream>>>(d4c, Wf2, dtb2, d5c);
        k_dec2<<<cd * 64, 256, 0, stream>>>(d5c, dw2, db2, outc);
    }
}